// Round 2
// baseline (5833.846 us; speedup 1.0000x reference)
//
#include <hip/hip_runtime.h>

#define HW 128
#define HW2 (128 * 128)
#define NEG 0.2f

__device__ __forceinline__ float lrelu(float v) { return v >= 0.f ? v : NEG * v; }

// ---------------------------------------------------------------------------
// Plain 3x3 conv, SAME padding, optional LeakyReLU.
// Block: 256 threads = 8x32 output tile; blockIdx.y picks CO output channels.
// Double-buffered LDS patch, register prefetch one channel ahead,
// ONE barrier per input channel.
// ---------------------------------------------------------------------------
template <int CO>
__global__ __launch_bounds__(256) void conv3x3_kernel(
    const float* __restrict__ in, const float* __restrict__ w,
    const float* __restrict__ bias, float* __restrict__ out,
    int Cin, int Cout, int do_leaky)
{
    __shared__ float sp[2][340];   // 10 x 34 patch, double buffered

    const int t = threadIdx.x;
    const int b = blockIdx.z;
    const int tile = blockIdx.x;          // 4 x-tiles, 16 y-tiles
    const int tx0 = (tile & 3) * 32;
    const int ty0 = (tile >> 2) * 8;
    const int lx = t & 31, ly = t >> 5;
    const int y = ty0 + ly, x = tx0 + lx;
    const int co0 = blockIdx.y * CO;

    // loader slots (channel-invariant): slot0 = t, slot1 = t + 256 (if < 340)
    const int r0 = t / 34, c0 = t - r0 * 34;
    const int gy0 = ty0 + r0 - 1, gx0 = tx0 + c0 - 1;
    const bool ok0 = gy0 >= 0 && gy0 < HW && gx0 >= 0 && gx0 < HW;
    const int goff0 = ok0 ? gy0 * HW + gx0 : 0;
    const int i1 = t + 256;
    const int r1 = i1 / 34, c1 = i1 - r1 * 34;
    const int gy1 = ty0 + r1 - 1, gx1 = tx0 + c1 - 1;
    const bool has1 = i1 < 340;
    const bool ok1 = has1 && gy1 >= 0 && gy1 < HW && gx1 >= 0 && gx1 < HW;
    const int goff1 = ok1 ? gy1 * HW + gx1 : 0;

    float acc[CO];
#pragma unroll
    for (int j = 0; j < CO; ++j) acc[j] = 0.f;

    const float* inb = in + (size_t)b * Cin * HW2;

    // preload channel 0
    {
        float v0 = ok0 ? inb[goff0] : 0.f;
        float v1 = ok1 ? inb[goff1] : 0.f;
        sp[0][t] = v0;
        if (has1) sp[0][i1] = v1;
    }
    __syncthreads();

    for (int c = 0; c < Cin; ++c) {
        const int cur = c & 1;
        // prefetch channel c+1 into registers (loads in flight during FMAs)
        float n0 = 0.f, n1 = 0.f;
        if (c + 1 < Cin) {
            const float* pl = inb + (size_t)(c + 1) * HW2;
            if (ok0) n0 = pl[goff0];
            if (ok1) n1 = pl[goff1];
        }

        float pv[9];
#pragma unroll
        for (int i = 0; i < 3; ++i)
#pragma unroll
            for (int j = 0; j < 3; ++j)
                pv[i * 3 + j] = sp[cur][(ly + i) * 34 + lx + j];

        const float* wc = w + ((size_t)co0 * Cin + c) * 9;
#pragma unroll
        for (int j = 0; j < CO; ++j) {
            const float* wj = wc + (size_t)j * Cin * 9;
#pragma unroll
            for (int k = 0; k < 9; ++k) acc[j] = fmaf(pv[k], wj[k], acc[j]);
        }

        if (c + 1 < Cin) {
            sp[1 - cur][t] = n0;
            if (has1) sp[1 - cur][i1] = n1;
        }
        __syncthreads();
    }

#pragma unroll
    for (int j = 0; j < CO; ++j) {
        float v = acc[j] + bias[co0 + j];
        if (do_leaky) v = lrelu(v);
        out[(((size_t)b * Cout + co0 + j) * HW + y) * HW + x] = v;
    }
}

// ---------------------------------------------------------------------------
// Deformable 3x3 conv (torchvision semantics), bias + LeakyReLU.
// Block: 256 threads = 64 pixels (8x8) x 4 co-sets (each COT channels).
// Phase 0: per-tap bilinear weights + PATCH-LOCAL indices in REGISTERS
// (channel-invariant). Fast path: input patch (14x16, pad 3) staged in LDS
// per channel (double-buffered, prefetched); gathers hit LDS. Block-uniform
// fallback to global gathers if any sample escapes the patch.
// ---------------------------------------------------------------------------
template <int COT>
__global__ __launch_bounds__(256) void deform_kernel(
    const float* __restrict__ in, const float* __restrict__ off,
    const float* __restrict__ w, const float* __restrict__ bias,
    float* __restrict__ out, int Cin, int Cout)
{
    constexpr int PH = 14, PW = 16;            // rows ty0-3 .. ty0+10
    __shared__ float patch[2][PH * PW];        // 1792 B
    __shared__ float s_val[64][12];            // 3072 B (9 padded to 12)

    const int t = threadIdx.x;
    const int b = blockIdx.z;
    const int tile = blockIdx.x;               // 16x16 grid of 8x8 tiles
    const int tx0 = (tile & 15) * 8;
    const int ty0 = (tile >> 4) * 8;
    const int px = t & 63;
    const int set = t >> 6;                    // wave-uniform
    const int y = ty0 + (px >> 3);
    const int x = tx0 + (px & 7);
    const int py0 = ty0 - 3, px0 = tx0 - 3;

    // ---- phase 0: tap params in registers (tasks t, t+256, t+512) ----
    float twt[3][4];
    int tidx[3][4];                            // global flat idx for now
    int tpp[3], tkk[3], tvalid[3];
    int allin = 1;
    const float* offb = off + (size_t)b * 18 * HW2;
#pragma unroll
    for (int s = 0; s < 3; ++s) {
        int task = t + s * 256;
        tvalid[s] = (task < 576);
        int task2 = tvalid[s] ? task : 0;
        int p = task2 / 9, k = task2 - p * 9;
        tpp[s] = p; tkk[s] = k;
        int yy = ty0 + (p >> 3), xx = tx0 + (p & 7);
        float dy = offb[(2 * k) * HW2 + yy * HW + xx];
        float dx = offb[(2 * k + 1) * HW2 + yy * HW + xx];
        float py = (float)(yy + k / 3 - 1) + dy;
        float pxx = (float)(xx + k % 3 - 1) + dx;
        float fy = floorf(py), fx = floorf(pxx);
        float wy = py - fy, wx = pxx - fx;
        int iy = (int)fy, ix = (int)fx;
        int iy1 = iy + 1, ix1 = ix + 1;
        float vy0 = (iy >= 0 && iy < HW) ? 1.f : 0.f;
        float vy1 = (iy1 >= 0 && iy1 < HW) ? 1.f : 0.f;
        float vx0 = (ix >= 0 && ix < HW) ? 1.f : 0.f;
        float vx1 = (ix1 >= 0 && ix1 < HW) ? 1.f : 0.f;
        int cy0 = min(max(iy, 0), HW - 1), cy1 = min(max(iy1, 0), HW - 1);
        int cx0 = min(max(ix, 0), HW - 1), cx1 = min(max(ix1, 0), HW - 1);
        twt[s][0] = (1.f - wy) * (1.f - wx) * vy0 * vx0;
        twt[s][1] = (1.f - wy) * wx * vy0 * vx1;
        twt[s][2] = wy * (1.f - wx) * vy1 * vx0;
        twt[s][3] = wy * wx * vy1 * vx1;
        tidx[s][0] = cy0 * HW + cx0;
        tidx[s][1] = cy0 * HW + cx1;
        tidx[s][2] = cy1 * HW + cx0;
        tidx[s][3] = cy1 * HW + cx1;
        // in-patch test on clamped coords
        bool ip = (cy0 >= py0) && (cy1 < py0 + PH) &&
                  (cx0 >= px0) && (cx1 < px0 + PW);
        if (!ip) allin = 0;
    }
    const int fast = __syncthreads_and(allin);

    float acc[COT];
#pragma unroll
    for (int j = 0; j < COT; ++j) acc[j] = 0.f;

    const float* inb = in + (size_t)b * Cin * HW2;

    if (fast) {
        // convert global flat idx -> patch-local idx (once)
        const int base = py0 * PW + px0;
#pragma unroll
        for (int s = 0; s < 3; ++s)
#pragma unroll
            for (int q = 0; q < 4; ++q) {
                int g = tidx[s][q];
                tidx[s][q] = (g >> 7) * PW + (g & 127) - base;
            }

        // patch loader (channel-invariant): thread t < 224 loads one element
        const int lr = t >> 4, lc = t & 15;
        const int pgy = py0 + lr, pgx = px0 + lc;
        const bool lvalid = (t < PH * PW) && pgy >= 0 && pgy < HW &&
                            pgx >= 0 && pgx < HW;
        const int goff = lvalid ? pgy * HW + pgx : 0;

        if (t < PH * PW) patch[0][t] = lvalid ? inb[goff] : 0.f;
        __syncthreads();

        for (int c = 0; c < Cin; ++c) {
            const int cur = c & 1;
            float nxt = 0.f;
            if (c + 1 < Cin && lvalid) nxt = inb[(size_t)(c + 1) * HW2 + goff];

            // phase A: bilinear gather from LDS patch -> s_val
            const float* P = patch[cur];
#pragma unroll
            for (int s = 0; s < 3; ++s) {
                if (tvalid[s]) {
                    float v = twt[s][0] * P[tidx[s][0]] +
                              twt[s][1] * P[tidx[s][1]] +
                              twt[s][2] * P[tidx[s][2]] +
                              twt[s][3] * P[tidx[s][3]];
                    s_val[tpp[s]][tkk[s]] = v;
                }
            }
            __syncthreads();

            // phase B: COT-channel dot + stage next patch
            if (c + 1 < Cin && t < PH * PW) patch[1 - cur][t] = nxt;

            float4 va = *(const float4*)&s_val[px][0];
            float4 vb = *(const float4*)&s_val[px][4];
            float v8 = s_val[px][8];
            float v[9] = {va.x, va.y, va.z, va.w, vb.x, vb.y, vb.z, vb.w, v8};

            const float* wc = w + ((size_t)(set * COT) * Cin + c) * 9;
#pragma unroll
            for (int j = 0; j < COT; ++j) {
                const float* wj = wc + (size_t)j * Cin * 9;
#pragma unroll
                for (int k = 0; k < 9; ++k) acc[j] = fmaf(v[k], wj[k], acc[j]);
            }
            __syncthreads();
        }
    } else {
        // slow path: gathers straight from global (correct for any offset)
        for (int c = 0; c < Cin; ++c) {
            const float* plane = inb + (size_t)c * HW2;
#pragma unroll
            for (int s = 0; s < 3; ++s) {
                if (tvalid[s]) {
                    float v = twt[s][0] * plane[tidx[s][0]] +
                              twt[s][1] * plane[tidx[s][1]] +
                              twt[s][2] * plane[tidx[s][2]] +
                              twt[s][3] * plane[tidx[s][3]];
                    s_val[tpp[s]][tkk[s]] = v;
                }
            }
            __syncthreads();

            float4 va = *(const float4*)&s_val[px][0];
            float4 vb = *(const float4*)&s_val[px][4];
            float v8 = s_val[px][8];
            float v[9] = {va.x, va.y, va.z, va.w, vb.x, vb.y, vb.z, vb.w, v8};

            const float* wc = w + ((size_t)(set * COT) * Cin + c) * 9;
#pragma unroll
            for (int j = 0; j < COT; ++j) {
                const float* wj = wc + (size_t)j * Cin * 9;
#pragma unroll
                for (int k = 0; k < 9; ++k) acc[j] = fmaf(v[k], wj[k], acc[j]);
            }
            __syncthreads();
        }
    }

#pragma unroll
    for (int j = 0; j < COT; ++j) {
        int co = set * COT + j;
        float v2 = lrelu(acc[j] + bias[co]);
        out[(((size_t)b * Cout + co) * HW + y) * HW + x] = v2;
    }
}

// ---------------------------------------------------------------------------
static void conv_launch(const float* in, const float* w, const float* b,
                        float* out, int Cin, int Cout, int leaky,
                        hipStream_t s)
{
    if (Cout % 32 == 0) {
        dim3 g(64, Cout / 32, 4);
        conv3x3_kernel<32><<<g, 256, 0, s>>>(in, w, b, out, Cin, Cout, leaky);
    } else {  // offset conv, Cout = 18
        dim3 g(64, 1, 4);
        conv3x3_kernel<18><<<g, 256, 0, s>>>(in, w, b, out, Cin, Cout, leaky);
    }
}

static void deform_launch(const float* in, const float* off, const float* w,
                          const float* b, float* out, int Cin, int Cout,
                          hipStream_t s)
{
    dim3 g(256, 1, 4);
    if (Cout == 128)
        deform_kernel<32><<<g, 256, 0, s>>>(in, off, w, b, out, Cin, Cout);
    else  // Cout == 64
        deform_kernel<16><<<g, 256, 0, s>>>(in, off, w, b, out, Cin, Cout);
}

extern "C" void kernel_launch(void* const* d_in, const int* in_sizes, int n_in,
                              void* d_out, int out_size, void* d_ws,
                              size_t ws_size, hipStream_t stream)
{
    const float* x = (const float*)d_in[0];
    const float* p[18];
    for (int i = 0; i < 18; ++i) p[i] = (const float*)d_in[1 + i];

    float* A = (float*)d_ws;                       // up to (4,128,128,128)
    float* Bf = A + (size_t)4 * 128 * HW2;         // up to (4,128,128,128)
    float* OFF = Bf + (size_t)4 * 128 * HW2;       // (4,18,128,128)
    float* OUT = (float*)d_out;

    // Stage 1: 64 -> 128
    conv_launch(x, p[0], p[1], A, 64, 128, 1, stream);
    conv_launch(A, p[2], p[3], OFF, 128, 18, 0, stream);
    deform_launch(A, OFF, p[4], p[5], Bf, 128, 128, stream);

    // Stage 2: 128 -> 128
    conv_launch(Bf, p[6], p[7], A, 128, 128, 1, stream);
    conv_launch(A, p[8], p[9], OFF, 128, 18, 0, stream);
    deform_launch(A, OFF, p[10], p[11], Bf, 128, 128, stream);

    // Stage 3: 128 -> 64
    conv_launch(Bf, p[12], p[13], A, 128, 64, 1, stream);
    conv_launch(A, p[14], p[15], OFF, 64, 18, 0, stream);
    deform_launch(A, OFF, p[16], p[17], OUT, 64, 64, stream);
}

// Round 3
// 1933.839 us; speedup vs baseline: 3.0167x; 3.0167x over previous
//
#include <hip/hip_runtime.h>

#define HW 128
#define HW2 16384
#define NEG 0.2f

typedef __attribute__((ext_vector_type(8))) short short8;
typedef __attribute__((ext_vector_type(4))) float f32x4;

__device__ __forceinline__ float lrelu(float v) { return v >= 0.f ? v : NEG * v; }
__device__ __forceinline__ unsigned short f2bf(float f) {
    unsigned int u = __float_as_uint(f);
    u = (u + 0x7fffu + ((u >> 16) & 1u)) >> 16;   // RNE
    return (unsigned short)u;
}
__device__ __forceinline__ float bf2f(unsigned short h) {
    return __uint_as_float(((unsigned int)h) << 16);
}
__device__ __forceinline__ float ldf(const float* p) { return *p; }
__device__ __forceinline__ float ldf(const unsigned short* p) { return bf2f(*p); }

// ---------------------------------------------------------------------------
// Weight cast fp32 -> bf16 (layout already [co][c*9+k] flat).
// ---------------------------------------------------------------------------
__global__ void cast_kernel(const float* __restrict__ src,
                            unsigned short* __restrict__ dst, int n)
{
    int i = blockIdx.x * 256 + threadIdx.x;
    if (i < n) dst[i] = f2bf(src[i]);
}

// ---------------------------------------------------------------------------
// im2col: act planes (T = float|bf16) -> col[b][px_t][K] bf16, K = Cin*9.
// Tile = 2x32 px (px_t tiled order: px_t = tile*64 + ly*32 + lx).
// Per channel: 4x34 patch in LDS; every 8 channels flush 64x72 chunk with
// 16B-aligned coalesced stores.
// ---------------------------------------------------------------------------
template <typename T>
__global__ __launch_bounds__(256) void im2col_kernel(
    const T* __restrict__ act, unsigned short* __restrict__ col, int Cin)
{
    __shared__ float patch[4 * 34];
    __shared__ unsigned short Cs[64 * 72];
    const int t = threadIdx.x;
    const int tile = blockIdx.x;
    const int b = blockIdx.z;
    const int y0 = (tile >> 2) * 2, x0 = (tile & 3) * 32;
    const int K = Cin * 9;

    int sp_[3], sk_[3], spi[3], svalid[3];
#pragma unroll
    for (int s = 0; s < 3; ++s) {
        int task = t + s * 256;
        svalid[s] = task < 576;
        if (!svalid[s]) task = 0;
        int p = task / 9, k = task - 9 * p;
        sp_[s] = p; sk_[s] = k;
        int ly = p >> 5, lx = p & 31, ky = k / 3, kx = k - 3 * ky;
        spi[s] = (ly + ky) * 34 + lx + kx;
    }
    const int pr = t / 34, pc = t - 34 * pr;
    const int gy = y0 - 1 + pr, gx = x0 - 1 + pc;
    const bool pok = (t < 136) && gy >= 0 && gy < HW && gx >= 0 && gx < HW;
    const int goff = pok ? gy * HW + gx : 0;
    const T* basep = act + (size_t)b * Cin * HW2;
    unsigned short* colb = col + ((size_t)b * HW2 + (size_t)tile * 64) * K;

    for (int c = 0; c < Cin; ++c) {
        if (t < 136) patch[t] = pok ? ldf(basep + (size_t)c * HW2 + goff) : 0.f;
        __syncthreads();
#pragma unroll
        for (int s = 0; s < 3; ++s)
            if (svalid[s])
                Cs[sp_[s] * 72 + (c & 7) * 9 + sk_[s]] = f2bf(patch[spi[s]]);
        __syncthreads();
        if ((c & 7) == 7) {
            int c0 = c - 7;
            for (int tt = t; tt < 576; tt += 256) {
                int pl = tt / 9, seg = tt - 9 * pl;
                *(uint4*)(colb + (size_t)pl * K + c0 * 9 + seg * 8) =
                    *(const uint4*)&Cs[pl * 72 + seg * 8];
            }
        }
    }
}

// ---------------------------------------------------------------------------
// Deformable gather: act (bf16 planes) + offsets -> col[b][px_t][K] bf16.
// Same tiling/flush as im2col. Bilinear in fp32; patch (10x40, margin 3)
// fast path; block-uniform global fallback.
// ---------------------------------------------------------------------------
__global__ __launch_bounds__(256) void gather_kernel(
    const unsigned short* __restrict__ act, const float* __restrict__ off,
    unsigned short* __restrict__ col, int Cin)
{
    __shared__ float patch[10 * 40];
    __shared__ unsigned short Cs[64 * 72];
    const int t = threadIdx.x;
    const int tile = blockIdx.x;
    const int b = blockIdx.z;
    const int y0 = (tile >> 2) * 2, x0 = (tile & 3) * 32;
    const int K = Cin * 9;

    float swt[3][4];
    int sidx[3][4];
    int sp_[3], sk_[3], svalid[3];
    int allin = 1;
    const float* offb = off + (size_t)b * 18 * HW2;
#pragma unroll
    for (int s = 0; s < 3; ++s) {
        int task = t + s * 256;
        svalid[s] = task < 576;
        int task2 = svalid[s] ? task : 0;
        int p = task2 / 9, k = task2 - 9 * p;
        sp_[s] = p; sk_[s] = k;
        int ly = p >> 5, lx = p & 31;
        int yy = y0 + ly, xx = x0 + lx;
        float dy = offb[(2 * k) * HW2 + yy * HW + xx];
        float dx = offb[(2 * k + 1) * HW2 + yy * HW + xx];
        float py = (float)(yy + k / 3 - 1) + dy;
        float px = (float)(xx + k % 3 - 1) + dx;
        float fy = floorf(py), fx = floorf(px);
        float wy = py - fy, wx = px - fx;
        int iy = (int)fy, ix = (int)fx, iy1 = iy + 1, ix1 = ix + 1;
        float vy0 = (iy >= 0 && iy < HW) ? 1.f : 0.f;
        float vy1 = (iy1 >= 0 && iy1 < HW) ? 1.f : 0.f;
        float vx0 = (ix >= 0 && ix < HW) ? 1.f : 0.f;
        float vx1 = (ix1 >= 0 && ix1 < HW) ? 1.f : 0.f;
        int cy0 = min(max(iy, 0), HW - 1), cy1 = min(max(iy1, 0), HW - 1);
        int cx0 = min(max(ix, 0), HW - 1), cx1 = min(max(ix1, 0), HW - 1);
        swt[s][0] = (1.f - wy) * (1.f - wx) * vy0 * vx0;
        swt[s][1] = (1.f - wy) * wx * vy0 * vx1;
        swt[s][2] = wy * (1.f - wx) * vy1 * vx0;
        swt[s][3] = wy * wx * vy1 * vx1;
        sidx[s][0] = cy0 * HW + cx0;
        sidx[s][1] = cy0 * HW + cx1;
        sidx[s][2] = cy1 * HW + cx0;
        sidx[s][3] = cy1 * HW + cx1;
        bool ip = cy0 >= y0 - 4 && cy1 <= y0 + 5 && cx0 >= x0 - 4 && cx1 <= x0 + 35;
        if (!ip) allin = 0;
    }
    const int fast = __syncthreads_and(allin);

    const unsigned short* basep = act + (size_t)b * Cin * HW2;
    unsigned short* colb = col + ((size_t)b * HW2 + (size_t)tile * 64) * K;

    if (fast) {
        const int pbase = (y0 - 4) * 40 + (x0 - 4);
#pragma unroll
        for (int s = 0; s < 3; ++s)
#pragma unroll
            for (int q = 0; q < 4; ++q) {
                int g = sidx[s][q];
                sidx[s][q] = (g >> 7) * 40 + (g & 127) - pbase;
            }
        const int r0 = t / 40, c0_ = t - 40 * r0;
        const int gy0_ = y0 - 4 + r0, gx0_ = x0 - 4 + c0_;
        const bool ok0 = gy0_ >= 0 && gy0_ < HW && gx0_ >= 0 && gx0_ < HW;
        const int go0 = ok0 ? gy0_ * HW + gx0_ : 0;
        const int t1 = t + 256;
        const int r1 = t1 / 40, c1_ = t1 - 40 * r1;
        const bool has1 = t1 < 400;
        const int gy1_ = y0 - 4 + r1, gx1_ = x0 - 4 + c1_;
        const bool ok1 = has1 && gy1_ >= 0 && gy1_ < HW && gx1_ >= 0 && gx1_ < HW;
        const int go1 = ok1 ? gy1_ * HW + gx1_ : 0;

        for (int c = 0; c < Cin; ++c) {
            const unsigned short* pl = basep + (size_t)c * HW2;
            patch[t] = ok0 ? bf2f(pl[go0]) : 0.f;
            if (has1) patch[t1] = ok1 ? bf2f(pl[go1]) : 0.f;
            __syncthreads();
#pragma unroll
            for (int s = 0; s < 3; ++s)
                if (svalid[s]) {
                    float v = swt[s][0] * patch[sidx[s][0]] +
                              swt[s][1] * patch[sidx[s][1]] +
                              swt[s][2] * patch[sidx[s][2]] +
                              swt[s][3] * patch[sidx[s][3]];
                    Cs[sp_[s] * 72 + (c & 7) * 9 + sk_[s]] = f2bf(v);
                }
            __syncthreads();
            if ((c & 7) == 7) {
                int c0 = c - 7;
                for (int tt = t; tt < 576; tt += 256) {
                    int pl2 = tt / 9, seg = tt - 9 * pl2;
                    *(uint4*)(colb + (size_t)pl2 * K + c0 * 9 + seg * 8) =
                        *(const uint4*)&Cs[pl2 * 72 + seg * 8];
                }
            }
        }
    } else {
        for (int c = 0; c < Cin; ++c) {
            const unsigned short* pl = basep + (size_t)c * HW2;
#pragma unroll
            for (int s = 0; s < 3; ++s)
                if (svalid[s]) {
                    float v = swt[s][0] * bf2f(pl[sidx[s][0]]) +
                              swt[s][1] * bf2f(pl[sidx[s][1]]) +
                              swt[s][2] * bf2f(pl[sidx[s][2]]) +
                              swt[s][3] * bf2f(pl[sidx[s][3]]);
                    Cs[sp_[s] * 72 + (c & 7) * 9 + sk_[s]] = f2bf(v);
                }
            __syncthreads();
            if ((c & 7) == 7) {
                int c0 = c - 7;
                for (int tt = t; tt < 576; tt += 256) {
                    int pl2 = tt / 9, seg = tt - 9 * pl2;
                    *(uint4*)(colb + (size_t)pl2 * K + c0 * 9 + seg * 8) =
                        *(const uint4*)&Cs[pl2 * 72 + seg * 8];
                }
                __syncthreads();
            }
        }
    }
}

// ---------------------------------------------------------------------------
// MFMA GEMM: out[b][co][px] = lrelu( sum_kk wmat[co][kk]*col[b][px][kk] + bias )
// A = weights (M=Cout, from LDS), B = col (N=64 px/block, direct global).
// MTW = M-tiles (16 co) per wave: 2 for Cout=128, 1 for Cout=64.
// mode 0: bf16 plane out via LDS-transposed coalesced stores; mode 1: fp32.
// ---------------------------------------------------------------------------
template <int MTW>
__global__ __launch_bounds__(256) void gemm_kernel(
    const unsigned short* __restrict__ col, const unsigned short* __restrict__ wmat,
    const float* __restrict__ bias, unsigned short* __restrict__ outb,
    float* __restrict__ outf, int K, int Cout, int mode)
{
    __shared__ unsigned short Ws[128 * 40];
    __shared__ unsigned short Es[128 * 72];
    const int t = threadIdx.x;
    const int tile = blockIdx.x, b = blockIdx.z;
    const int lane = t & 63, wv = t >> 6, quad = lane >> 4, l15 = lane & 15;
    const int y0 = (tile >> 2) * 2, x0 = (tile & 3) * 32;

    f32x4 acc[MTW][4];
#pragma unroll
    for (int m = 0; m < MTW; ++m)
#pragma unroll
        for (int nt = 0; nt < 4; ++nt) acc[m][nt] = (f32x4)(0.f);

    const unsigned short* colb = col + ((size_t)b * HW2 + (size_t)tile * 64) * K;
    const unsigned short* bp[4];
#pragma unroll
    for (int nt = 0; nt < 4; ++nt)
        bp[nt] = colb + (size_t)(nt * 16 + l15) * K + quad * 8;

    short8 bcur[4], bnext[4];
#pragma unroll
    for (int nt = 0; nt < 4; ++nt) bcur[nt] = *(const short8*)bp[nt];

    const int iters = K >> 5;
    for (int it = 0; it < iters; ++it) {
        const int kk0 = it << 5;
        for (int tt = t; tt < Cout * 4; tt += 256) {
            int co = tt >> 2, seg = tt & 3;
            *(uint4*)&Ws[co * 40 + seg * 8] =
                *(const uint4*)(wmat + (size_t)co * K + kk0 + seg * 8);
        }
        __syncthreads();
        if (it + 1 < iters) {
#pragma unroll
            for (int nt = 0; nt < 4; ++nt)
                bnext[nt] = *(const short8*)(bp[nt] + kk0 + 32);
        }
#pragma unroll
        for (int m = 0; m < MTW; ++m) {
            int cb = (wv * MTW + m) * 16;
            short8 a = *(const short8*)&Ws[(cb + l15) * 40 + quad * 8];
#pragma unroll
            for (int nt = 0; nt < 4; ++nt)
                acc[m][nt] = __builtin_amdgcn_mfma_f32_16x16x32_bf16(
                    a, bcur[nt], acc[m][nt], 0, 0, 0);
        }
        __syncthreads();
#pragma unroll
        for (int nt = 0; nt < 4; ++nt) bcur[nt] = bnext[nt];
    }

    if (mode == 0) {
#pragma unroll
        for (int m = 0; m < MTW; ++m) {
            int cb = (wv * MTW + m) * 16;
#pragma unroll
            for (int nt = 0; nt < 4; ++nt)
#pragma unroll
                for (int r = 0; r < 4; ++r) {
                    int co = cb + quad * 4 + r;
                    int pxl = nt * 16 + l15;
                    float v = lrelu(acc[m][nt][r] + bias[co]);
                    Es[co * 72 + pxl] = f2bf(v);
                }
        }
        __syncthreads();
        unsigned short* ob = outb + (size_t)b * Cout * HW2;
        for (int tt = t; tt < Cout * 8; tt += 256) {
            int co = tt >> 3, seg = tt & 7;
            int ly = seg >> 2, lxb = (seg & 3) * 8;
            *(uint4*)(ob + (size_t)co * HW2 + (y0 + ly) * HW + x0 + lxb) =
                *(const uint4*)&Es[co * 72 + seg * 8];
        }
    } else {
        float* of = outf + (size_t)b * Cout * HW2;
#pragma unroll
        for (int m = 0; m < MTW; ++m) {
            int cb = (wv * MTW + m) * 16;
#pragma unroll
            for (int nt = 0; nt < 4; ++nt)
#pragma unroll
                for (int r = 0; r < 4; ++r) {
                    int co = cb + quad * 4 + r;
                    int pxl = nt * 16 + l15;
                    int yy = y0 + (pxl >> 5), xx = x0 + (pxl & 31);
                    of[(size_t)co * HW2 + yy * HW + xx] =
                        lrelu(acc[m][nt][r] + bias[co]);
                }
        }
    }
}

// ---------------------------------------------------------------------------
// Offset conv (Cout=18), fp32 math, bf16 input planes, fp32 out, no leaky.
// R0-proven single-buffered structure.
// ---------------------------------------------------------------------------
template <typename T>
__global__ __launch_bounds__(256) void offconv_kernel(
    const T* __restrict__ in, const float* __restrict__ w,
    const float* __restrict__ bias, float* __restrict__ out, int Cin)
{
    constexpr int CO = 18;
    __shared__ float sp[10][34];
    const int t = threadIdx.x;
    const int b = blockIdx.z;
    const int tile = blockIdx.x;
    const int tx0 = (tile & 3) * 32;
    const int ty0 = (tile >> 2) * 8;
    const int lx = t & 31, ly = t >> 5;
    const int y = ty0 + ly, x = tx0 + lx;

    float acc[CO];
#pragma unroll
    for (int j = 0; j < CO; ++j) acc[j] = 0.f;

    const T* inb = in + (size_t)b * Cin * HW2;

    for (int c = 0; c < Cin; ++c) {
        const T* plane = inb + (size_t)c * HW2;
        for (int i = t; i < 340; i += 256) {
            int r = i / 34, cc = i - r * 34;
            int gy = ty0 + r - 1, gx = tx0 + cc - 1;
            float v = 0.f;
            if (gy >= 0 && gy < HW && gx >= 0 && gx < HW)
                v = ldf(plane + gy * HW + gx);
            sp[r][cc] = v;
        }
        __syncthreads();

        float pv[9];
#pragma unroll
        for (int i = 0; i < 3; ++i)
#pragma unroll
            for (int j = 0; j < 3; ++j) pv[i * 3 + j] = sp[ly + i][lx + j];

        const float* wc = w + (size_t)c * 9;
#pragma unroll
        for (int j = 0; j < CO; ++j) {
            const float* wj = wc + (size_t)j * Cin * 9;
#pragma unroll
            for (int k = 0; k < 9; ++k) acc[j] = fmaf(pv[k], wj[k], acc[j]);
        }
        __syncthreads();
    }

#pragma unroll
    for (int j = 0; j < CO; ++j)
        out[(((size_t)b * CO + j) * HW + y) * HW + x] = acc[j] + bias[j];
}

// ---------------------------------------------------------------------------
extern "C" void kernel_launch(void* const* d_in, const int* in_sizes, int n_in,
                              void* d_out, int out_size, void* d_ws,
                              size_t ws_size, hipStream_t stream)
{
    const float* x = (const float*)d_in[0];
    const float* p[18];
    for (int i = 0; i < 18; ++i) p[i] = (const float*)d_in[1 + i];

    char* ws = (char*)d_ws;
    unsigned short* ACT = (unsigned short*)ws;            // 4*128*HW2*2 = 16.78 MB
    float* OFF = (float*)(ws + 16777216);                 // 4*18*HW2*4  = 4.72 MB
    unsigned short* WB = (unsigned short*)(ws + 16777216 + 4718592);  // 1.25 MB
    size_t fixed = 16777216 + 4718592 + 1253376;
    unsigned short* COL = (unsigned short*)(ws + fixed);
    const size_t colper = (size_t)HW2 * 1152 * 2;         // 37.75 MB / batch
    int nbc = 1;
    if (ws_size > fixed) {
        long a = (long)((ws_size - fixed) / colper);
        nbc = a < 1 ? 1 : (a > 4 ? 4 : (int)a);
    }

    // weight sub-buffers (bf16)
    unsigned short* Wc1 = WB;                 // 128*576
    unsigned short* Wd1 = Wc1 + 73728;        // 128*1152
    unsigned short* Wc2 = Wd1 + 147456;       // 128*1152
    unsigned short* Wd2 = Wc2 + 147456;       // 128*1152
    unsigned short* Wc3 = Wd2 + 147456;       // 64*1152
    unsigned short* Wd3 = Wc3 + 73728;        // 64*576

    cast_kernel<<<dim3(288), 256, 0, stream>>>(p[0], Wc1, 73728);
    cast_kernel<<<dim3(576), 256, 0, stream>>>(p[4], Wd1, 147456);
    cast_kernel<<<dim3(576), 256, 0, stream>>>(p[6], Wc2, 147456);
    cast_kernel<<<dim3(576), 256, 0, stream>>>(p[10], Wd2, 147456);
    cast_kernel<<<dim3(288), 256, 0, stream>>>(p[12], Wc3, 73728);
    cast_kernel<<<dim3(144), 256, 0, stream>>>(p[16], Wd3, 36864);

    struct Stage {
        int Cin, Cout;
        const unsigned short *Wc, *Wd;
        const float *cb, *ob, *ow, *db;
    };
    Stage st[3] = {
        {64, 128, Wc1, Wd1, p[1], p[3], p[2], p[5]},
        {128, 128, Wc2, Wd2, p[7], p[9], p[8], p[11]},
        {128, 64, Wc3, Wd3, p[13], p[15], p[14], p[17]},
    };

    for (int s = 0; s < 3; ++s) {
        const int Cin = st[s].Cin, Cout = st[s].Cout;
        const int Kc = Cin * 9, Kd = Cout * 9;

        // ---- conv (im2col + GEMM) ----
        for (int b0 = 0; b0 < 4; b0 += nbc) {
            int nb = (4 - b0) < nbc ? (4 - b0) : nbc;
            dim3 g(256, 1, nb);
            if (s == 0)
                im2col_kernel<float><<<g, 256, 0, stream>>>(
                    x + (size_t)b0 * Cin * HW2, COL, Cin);
            else
                im2col_kernel<unsigned short><<<g, 256, 0, stream>>>(
                    ACT + (size_t)b0 * Cin * HW2, COL, Cin);
            if (Cout == 128)
                gemm_kernel<2><<<g, 256, 0, stream>>>(
                    COL, st[s].Wc, st[s].cb, ACT + (size_t)b0 * Cout * HW2,
                    nullptr, Kc, Cout, 0);
            else
                gemm_kernel<1><<<g, 256, 0, stream>>>(
                    COL, st[s].Wc, st[s].cb, ACT + (size_t)b0 * Cout * HW2,
                    nullptr, Kc, Cout, 0);
        }

        // ---- offset conv (full batch) ----
        offconv_kernel<unsigned short><<<dim3(64, 1, 4), 256, 0, stream>>>(
            ACT, st[s].ow, st[s].ob, OFF, Cout);

        // ---- deform (gather + GEMM) ----
        for (int b0 = 0; b0 < 4; b0 += nbc) {
            int nb = (4 - b0) < nbc ? (4 - b0) : nbc;
            dim3 g(256, 1, nb);
            gather_kernel<<<g, 256, 0, stream>>>(
                ACT + (size_t)b0 * Cout * HW2, OFF + (size_t)b0 * 18 * HW2,
                COL, Cout);
            if (s == 2) {
                gemm_kernel<1><<<g, 256, 0, stream>>>(
                    COL, st[s].Wd, st[s].db, nullptr,
                    (float*)d_out + (size_t)b0 * 64 * HW2, Kd, 64, 1);
            } else {
                gemm_kernel<2><<<g, 256, 0, stream>>>(
                    COL, st[s].Wd, st[s].db, ACT + (size_t)b0 * Cout * HW2,
                    nullptr, Kd, 128, 0);
            }
        }
    }
}

// Round 4
// 1447.170 us; speedup vs baseline: 4.0312x; 1.3363x over previous
//
#include <hip/hip_runtime.h>

#define HW 128
#define HW2 16384
#define NEG 0.2f

typedef __attribute__((ext_vector_type(8))) short short8;
typedef __attribute__((ext_vector_type(4))) float f32x4;

__device__ __forceinline__ float lrelu(float v) { return v >= 0.f ? v : NEG * v; }
__device__ __forceinline__ unsigned short f2bf(float f) {
    unsigned int u = __float_as_uint(f);
    u = (u + 0x7fffu + ((u >> 16) & 1u)) >> 16;   // RNE
    return (unsigned short)u;
}
__device__ __forceinline__ float bf2f(unsigned short h) {
    return __uint_as_float(((unsigned int)h) << 16);
}
__device__ __forceinline__ float ldf(const float* p) { return *p; }
__device__ __forceinline__ float ldf(const unsigned short* p) { return bf2f(*p); }

// ---------------------------------------------------------------------------
// Combined weight cast fp32 -> bf16 (9 segments, one launch).
// dst[i] = i < valid ? bf16(src[i]) : 0   (zero-pads the offset weights to M=64)
// ---------------------------------------------------------------------------
struct CastSeg { const float* s; unsigned short* d; int n; int valid; };
struct CastArgs { CastSeg seg[9]; };

__global__ void cast_all_kernel(CastArgs a)
{
    const CastSeg& sg = a.seg[blockIdx.y];
    int i = blockIdx.x * 256 + threadIdx.x;
    if (i < sg.n) sg.d[i] = (i < sg.valid) ? f2bf(sg.s[i]) : (unsigned short)0;
}

// ---------------------------------------------------------------------------
// im2col: act planes (T = float|bf16) -> col[b][px_t][K] bf16, K = Cin*9.
// Tile = 2x32 px (px_t tiled order: px_t = tile*64 + ly*32 + lx).
// Per channel: 4x34 patch in LDS; every 8 channels flush 64x72 chunk with
// 16B-aligned coalesced stores.
// ---------------------------------------------------------------------------
template <typename T>
__global__ __launch_bounds__(256) void im2col_kernel(
    const T* __restrict__ act, unsigned short* __restrict__ col, int Cin)
{
    __shared__ float patch[4 * 34];
    __shared__ unsigned short Cs[64 * 72];
    const int t = threadIdx.x;
    const int tile = blockIdx.x;
    const int b = blockIdx.z;
    const int y0 = (tile >> 2) * 2, x0 = (tile & 3) * 32;
    const int K = Cin * 9;

    int sp_[3], sk_[3], spi[3], svalid[3];
#pragma unroll
    for (int s = 0; s < 3; ++s) {
        int task = t + s * 256;
        svalid[s] = task < 576;
        if (!svalid[s]) task = 0;
        int p = task / 9, k = task - 9 * p;
        sp_[s] = p; sk_[s] = k;
        int ly = p >> 5, lx = p & 31, ky = k / 3, kx = k - 3 * ky;
        spi[s] = (ly + ky) * 34 + lx + kx;
    }
    const int pr = t / 34, pc = t - 34 * pr;
    const int gy = y0 - 1 + pr, gx = x0 - 1 + pc;
    const bool pok = (t < 136) && gy >= 0 && gy < HW && gx >= 0 && gx < HW;
    const int goff = pok ? gy * HW + gx : 0;
    const T* basep = act + (size_t)b * Cin * HW2;
    unsigned short* colb = col + ((size_t)b * HW2 + (size_t)tile * 64) * K;

    for (int c = 0; c < Cin; ++c) {
        if (t < 136) patch[t] = pok ? ldf(basep + (size_t)c * HW2 + goff) : 0.f;
        __syncthreads();
#pragma unroll
        for (int s = 0; s < 3; ++s)
            if (svalid[s])
                Cs[sp_[s] * 72 + (c & 7) * 9 + sk_[s]] = f2bf(patch[spi[s]]);
        __syncthreads();
        if ((c & 7) == 7) {
            int c0 = c - 7;
            for (int tt = t; tt < 576; tt += 256) {
                int pl = tt / 9, seg = tt - 9 * pl;
                *(uint4*)(colb + (size_t)pl * K + c0 * 9 + seg * 8) =
                    *(const uint4*)&Cs[pl * 72 + seg * 8];
            }
        }
    }
}

// ---------------------------------------------------------------------------
// Deformable gather: act (bf16 planes) + offsets -> col[b][px_t][K] bf16.
// Same tiling/flush as im2col. Bilinear in fp32; patch (10x40, margin 3)
// fast path; block-uniform global fallback.
// ---------------------------------------------------------------------------
__global__ __launch_bounds__(256) void gather_kernel(
    const unsigned short* __restrict__ act, const float* __restrict__ off,
    unsigned short* __restrict__ col, int Cin)
{
    __shared__ float patch[10 * 40];
    __shared__ unsigned short Cs[64 * 72];
    const int t = threadIdx.x;
    const int tile = blockIdx.x;
    const int b = blockIdx.z;
    const int y0 = (tile >> 2) * 2, x0 = (tile & 3) * 32;
    const int K = Cin * 9;

    float swt[3][4];
    int sidx[3][4];
    int sp_[3], sk_[3], svalid[3];
    int allin = 1;
    const float* offb = off + (size_t)b * 18 * HW2;
#pragma unroll
    for (int s = 0; s < 3; ++s) {
        int task = t + s * 256;
        svalid[s] = task < 576;
        int task2 = svalid[s] ? task : 0;
        int p = task2 / 9, k = task2 - 9 * p;
        sp_[s] = p; sk_[s] = k;
        int ly = p >> 5, lx = p & 31;
        int yy = y0 + ly, xx = x0 + lx;
        float dy = offb[(2 * k) * HW2 + yy * HW + xx];
        float dx = offb[(2 * k + 1) * HW2 + yy * HW + xx];
        float py = (float)(yy + k / 3 - 1) + dy;
        float px = (float)(xx + k % 3 - 1) + dx;
        float fy = floorf(py), fx = floorf(px);
        float wy = py - fy, wx = px - fx;
        int iy = (int)fy, ix = (int)fx, iy1 = iy + 1, ix1 = ix + 1;
        float vy0 = (iy >= 0 && iy < HW) ? 1.f : 0.f;
        float vy1 = (iy1 >= 0 && iy1 < HW) ? 1.f : 0.f;
        float vx0 = (ix >= 0 && ix < HW) ? 1.f : 0.f;
        float vx1 = (ix1 >= 0 && ix1 < HW) ? 1.f : 0.f;
        int cy0 = min(max(iy, 0), HW - 1), cy1 = min(max(iy1, 0), HW - 1);
        int cx0 = min(max(ix, 0), HW - 1), cx1 = min(max(ix1, 0), HW - 1);
        swt[s][0] = (1.f - wy) * (1.f - wx) * vy0 * vx0;
        swt[s][1] = (1.f - wy) * wx * vy0 * vx1;
        swt[s][2] = wy * (1.f - wx) * vy1 * vx0;
        swt[s][3] = wy * wx * vy1 * vx1;
        sidx[s][0] = cy0 * HW + cx0;
        sidx[s][1] = cy0 * HW + cx1;
        sidx[s][2] = cy1 * HW + cx0;
        sidx[s][3] = cy1 * HW + cx1;
        bool ip = cy0 >= y0 - 4 && cy1 <= y0 + 5 && cx0 >= x0 - 4 && cx1 <= x0 + 35;
        if (!ip) allin = 0;
    }
    const int fast = __syncthreads_and(allin);

    const unsigned short* basep = act + (size_t)b * Cin * HW2;
    unsigned short* colb = col + ((size_t)b * HW2 + (size_t)tile * 64) * K;

    if (fast) {
        const int pbase = (y0 - 4) * 40 + (x0 - 4);
#pragma unroll
        for (int s = 0; s < 3; ++s)
#pragma unroll
            for (int q = 0; q < 4; ++q) {
                int g = sidx[s][q];
                sidx[s][q] = (g >> 7) * 40 + (g & 127) - pbase;
            }
        const int r0 = t / 40, c0_ = t - 40 * r0;
        const int gy0_ = y0 - 4 + r0, gx0_ = x0 - 4 + c0_;
        const bool ok0 = gy0_ >= 0 && gy0_ < HW && gx0_ >= 0 && gx0_ < HW;
        const int go0 = ok0 ? gy0_ * HW + gx0_ : 0;
        const int t1 = t + 256;
        const int r1 = t1 / 40, c1_ = t1 - 40 * r1;
        const bool has1 = t1 < 400;
        const int gy1_ = y0 - 4 + r1, gx1_ = x0 - 4 + c1_;
        const bool ok1 = has1 && gy1_ >= 0 && gy1_ < HW && gx1_ >= 0 && gx1_ < HW;
        const int go1 = ok1 ? gy1_ * HW + gx1_ : 0;

        for (int c = 0; c < Cin; ++c) {
            const unsigned short* pl = basep + (size_t)c * HW2;
            patch[t] = ok0 ? bf2f(pl[go0]) : 0.f;
            if (has1) patch[t1] = ok1 ? bf2f(pl[go1]) : 0.f;
            __syncthreads();
#pragma unroll
            for (int s = 0; s < 3; ++s)
                if (svalid[s]) {
                    float v = swt[s][0] * patch[sidx[s][0]] +
                              swt[s][1] * patch[sidx[s][1]] +
                              swt[s][2] * patch[sidx[s][2]] +
                              swt[s][3] * patch[sidx[s][3]];
                    Cs[sp_[s] * 72 + (c & 7) * 9 + sk_[s]] = f2bf(v);
                }
            __syncthreads();
            if ((c & 7) == 7) {
                int c0 = c - 7;
                for (int tt = t; tt < 576; tt += 256) {
                    int pl2 = tt / 9, seg = tt - 9 * pl2;
                    *(uint4*)(colb + (size_t)pl2 * K + c0 * 9 + seg * 8) =
                        *(const uint4*)&Cs[pl2 * 72 + seg * 8];
                }
            }
        }
    } else {
        for (int c = 0; c < Cin; ++c) {
            const unsigned short* pl = basep + (size_t)c * HW2;
#pragma unroll
            for (int s = 0; s < 3; ++s)
                if (svalid[s]) {
                    float v = swt[s][0] * bf2f(pl[sidx[s][0]]) +
                              swt[s][1] * bf2f(pl[sidx[s][1]]) +
                              swt[s][2] * bf2f(pl[sidx[s][2]]) +
                              swt[s][3] * bf2f(pl[sidx[s][3]]);
                    Cs[sp_[s] * 72 + (c & 7) * 9 + sk_[s]] = f2bf(v);
                }
            __syncthreads();
            if ((c & 7) == 7) {
                int c0 = c - 7;
                for (int tt = t; tt < 576; tt += 256) {
                    int pl2 = tt / 9, seg = tt - 9 * pl2;
                    *(uint4*)(colb + (size_t)pl2 * K + c0 * 9 + seg * 8) =
                        *(const uint4*)&Cs[pl2 * 72 + seg * 8];
                }
                __syncthreads();
            }
        }
    }
}

// ---------------------------------------------------------------------------
// MFMA GEMM: out[b][co][px] = act( sum_kk wmat[co][kk]*col[b][px][kk] + bias )
// A = weights (M=Cout rows, from LDS), B = col (N=64 px/block, direct global).
// MTW = M-tiles (16 co) per wave: 2 for Cout=128, 1 for Cout=64.
// mode 0: bf16 plane out (leaky) via LDS-transposed coalesced stores
// mode 1: fp32 plane out (leaky), stride Cout
// mode 2: fp32 plane out, NO leaky, only co<18 stored, stride 18 (offset conv)
// ---------------------------------------------------------------------------
template <int MTW>
__global__ __launch_bounds__(256) void gemm_kernel(
    const unsigned short* __restrict__ col, const unsigned short* __restrict__ wmat,
    const float* __restrict__ bias, unsigned short* __restrict__ outb,
    float* __restrict__ outf, int K, int Cout, int mode)
{
    __shared__ unsigned short Ws[128 * 40];
    __shared__ unsigned short Es[128 * 72];
    const int t = threadIdx.x;
    const int tile = blockIdx.x, b = blockIdx.z;
    const int lane = t & 63, wv = t >> 6, quad = lane >> 4, l15 = lane & 15;
    const int y0 = (tile >> 2) * 2, x0 = (tile & 3) * 32;

    f32x4 acc[MTW][4];
#pragma unroll
    for (int m = 0; m < MTW; ++m)
#pragma unroll
        for (int nt = 0; nt < 4; ++nt) acc[m][nt] = (f32x4)(0.f);

    const unsigned short* colb = col + ((size_t)b * HW2 + (size_t)tile * 64) * K;
    const unsigned short* bp[4];
#pragma unroll
    for (int nt = 0; nt < 4; ++nt)
        bp[nt] = colb + (size_t)(nt * 16 + l15) * K + quad * 8;

    short8 bcur[4], bnext[4];
#pragma unroll
    for (int nt = 0; nt < 4; ++nt) bcur[nt] = *(const short8*)bp[nt];

    const int iters = K >> 5;
    for (int it = 0; it < iters; ++it) {
        const int kk0 = it << 5;
        for (int tt = t; tt < Cout * 4; tt += 256) {
            int co = tt >> 2, seg = tt & 3;
            *(uint4*)&Ws[co * 40 + seg * 8] =
                *(const uint4*)(wmat + (size_t)co * K + kk0 + seg * 8);
        }
        __syncthreads();
        if (it + 1 < iters) {
#pragma unroll
            for (int nt = 0; nt < 4; ++nt)
                bnext[nt] = *(const short8*)(bp[nt] + kk0 + 32);
        }
#pragma unroll
        for (int m = 0; m < MTW; ++m) {
            int cb = (wv * MTW + m) * 16;
            short8 a = *(const short8*)&Ws[(cb + l15) * 40 + quad * 8];
#pragma unroll
            for (int nt = 0; nt < 4; ++nt)
                acc[m][nt] = __builtin_amdgcn_mfma_f32_16x16x32_bf16(
                    a, bcur[nt], acc[m][nt], 0, 0, 0);
        }
        __syncthreads();
#pragma unroll
        for (int nt = 0; nt < 4; ++nt) bcur[nt] = bnext[nt];
    }

    if (mode == 0) {
#pragma unroll
        for (int m = 0; m < MTW; ++m) {
            int cb = (wv * MTW + m) * 16;
#pragma unroll
            for (int nt = 0; nt < 4; ++nt)
#pragma unroll
                for (int r = 0; r < 4; ++r) {
                    int co = cb + quad * 4 + r;
                    int pxl = nt * 16 + l15;
                    float v = lrelu(acc[m][nt][r] + bias[co]);
                    Es[co * 72 + pxl] = f2bf(v);
                }
        }
        __syncthreads();
        unsigned short* ob = outb + (size_t)b * Cout * HW2;
        for (int tt = t; tt < Cout * 8; tt += 256) {
            int co = tt >> 3, seg = tt & 7;
            int ly = seg >> 2, lxb = (seg & 3) * 8;
            *(uint4*)(ob + (size_t)co * HW2 + (y0 + ly) * HW + x0 + lxb) =
                *(const uint4*)&Es[co * 72 + seg * 8];
        }
    } else {
        const int cstride = (mode == 2) ? 18 : Cout;
        float* of = outf + (size_t)b * cstride * HW2;
#pragma unroll
        for (int m = 0; m < MTW; ++m) {
            int cb = (wv * MTW + m) * 16;
#pragma unroll
            for (int nt = 0; nt < 4; ++nt)
#pragma unroll
                for (int r = 0; r < 4; ++r) {
                    int co = cb + quad * 4 + r;
                    if (mode == 2 && co >= 18) continue;
                    int pxl = nt * 16 + l15;
                    int yy = y0 + (pxl >> 5), xx = x0 + (pxl & 31);
                    float v = acc[m][nt][r] + bias[co];
                    if (mode == 1) v = lrelu(v);
                    of[(size_t)co * HW2 + yy * HW + xx] = v;
                }
        }
    }
}

// ---------------------------------------------------------------------------
extern "C" void kernel_launch(void* const* d_in, const int* in_sizes, int n_in,
                              void* d_out, int out_size, void* d_ws,
                              size_t ws_size, hipStream_t stream)
{
    const float* x = (const float*)d_in[0];
    const float* p[18];
    for (int i = 0; i < 18; ++i) p[i] = (const float*)d_in[1 + i];

    char* ws = (char*)d_ws;
    unsigned short* ACT = (unsigned short*)ws;            // 4*128*HW2*2 = 16.78 MB
    float* OFF = (float*)(ws + 16777216);                 // 4*18*HW2*4  = 4.72 MB
    unsigned short* WB = (unsigned short*)(ws + 16777216 + 4718592);
    // weight sub-buffers (bf16): conv/deform + padded offset weights (M=64)
    unsigned short* Wc1 = WB;                  // 128*576  = 73728
    unsigned short* Wd1 = Wc1 + 73728;         // 128*1152 = 147456
    unsigned short* Wc2 = Wd1 + 147456;        // 128*1152
    unsigned short* Wd2 = Wc2 + 147456;        // 128*1152
    unsigned short* Wc3 = Wd2 + 147456;        // 64*1152  = 73728
    unsigned short* Wd3 = Wc3 + 73728;         // 64*576   = 36864
    unsigned short* Wo1 = Wd3 + 36864;         // 64*1152  = 73728 (pad from 18)
    unsigned short* Wo2 = Wo1 + 73728;         // 64*1152
    unsigned short* Wo3 = Wo2 + 73728;         // 64*576   = 36864
    size_t fixed = 16777216 + 4718592 + 2 * (626688 + 184320);
    unsigned short* COL = (unsigned short*)(ws + ((fixed + 255) & ~(size_t)255));
    fixed = (fixed + 255) & ~(size_t)255;
    const size_t colper = (size_t)HW2 * 1152 * 2;         // 37.75 MB / batch
    int nbc = 1;
    if (ws_size > fixed) {
        long a = (long)((ws_size - fixed) / colper);
        nbc = a < 1 ? 1 : (a > 4 ? 4 : (int)a);
    }

    // one launch for all weight casts (+ zero-padding of offset weights)
    CastArgs ca;
    ca.seg[0] = {p[0],  Wc1, 73728,  73728};
    ca.seg[1] = {p[4],  Wd1, 147456, 147456};
    ca.seg[2] = {p[6],  Wc2, 147456, 147456};
    ca.seg[3] = {p[10], Wd2, 147456, 147456};
    ca.seg[4] = {p[12], Wc3, 73728,  73728};
    ca.seg[5] = {p[16], Wd3, 36864,  36864};
    ca.seg[6] = {p[2],  Wo1, 73728,  18 * 1152};
    ca.seg[7] = {p[8],  Wo2, 73728,  18 * 1152};
    ca.seg[8] = {p[14], Wo3, 36864,  18 * 576};
    cast_all_kernel<<<dim3(576, 9), 256, 0, stream>>>(ca);

    struct Stage {
        int Cin, Cout;
        const unsigned short *Wc, *Wd, *Wo;
        const float *cb, *ob, *db;
    };
    Stage st[3] = {
        {64, 128, Wc1, Wd1, Wo1, p[1], p[3], p[5]},
        {128, 128, Wc2, Wd2, Wo2, p[7], p[9], p[11]},
        {128, 64, Wc3, Wd3, Wo3, p[13], p[15], p[17]},
    };

    for (int s = 0; s < 3; ++s) {
        const int Cin = st[s].Cin, Cout = st[s].Cout;
        const int Kc = Cin * 9, Kd = Cout * 9;

        // ---- conv (im2col + GEMM) ----
        for (int b0 = 0; b0 < 4; b0 += nbc) {
            int nb = (4 - b0) < nbc ? (4 - b0) : nbc;
            dim3 g(256, 1, nb);
            if (s == 0)
                im2col_kernel<float><<<g, 256, 0, stream>>>(
                    x + (size_t)b0 * Cin * HW2, COL, Cin);
            else
                im2col_kernel<unsigned short><<<g, 256, 0, stream>>>(
                    ACT + (size_t)b0 * Cin * HW2, COL, Cin);
            if (Cout == 128)
                gemm_kernel<2><<<g, 256, 0, stream>>>(
                    COL, st[s].Wc, st[s].cb, ACT + (size_t)b0 * Cout * HW2,
                    nullptr, Kc, Cout, 0);
            else
                gemm_kernel<1><<<g, 256, 0, stream>>>(
                    COL, st[s].Wc, st[s].cb, ACT + (size_t)b0 * Cout * HW2,
                    nullptr, Kc, Cout, 0);
        }

        // ---- offset conv (im2col(h) + padded-M GEMM, fp32 out, no leaky) ----
        for (int b0 = 0; b0 < 4; b0 += nbc) {
            int nb = (4 - b0) < nbc ? (4 - b0) : nbc;
            dim3 g(256, 1, nb);
            im2col_kernel<unsigned short><<<g, 256, 0, stream>>>(
                ACT + (size_t)b0 * Cout * HW2, COL, Cout);
            gemm_kernel<1><<<g, 256, 0, stream>>>(
                COL, st[s].Wo, st[s].ob, nullptr,
                OFF + (size_t)b0 * 18 * HW2, Kd, 64, 2);
        }

        // ---- deform (gather + GEMM) ----
        for (int b0 = 0; b0 < 4; b0 += nbc) {
            int nb = (4 - b0) < nbc ? (4 - b0) : nbc;
            dim3 g(256, 1, nb);
            gather_kernel<<<g, 256, 0, stream>>>(
                ACT + (size_t)b0 * Cout * HW2, OFF + (size_t)b0 * 18 * HW2,
                COL, Cout);
            if (s == 2) {
                gemm_kernel<1><<<g, 256, 0, stream>>>(
                    COL, st[s].Wd, st[s].db, nullptr,
                    (float*)d_out + (size_t)b0 * 64 * HW2, Kd, 64, 1);
            } else {
                gemm_kernel<2><<<g, 256, 0, stream>>>(
                    COL, st[s].Wd, st[s].db, ACT + (size_t)b0 * Cout * HW2,
                    nullptr, Kd, 128, 0);
            }
        }
    }
}

// Round 5
// 812.876 us; speedup vs baseline: 7.1768x; 1.7803x over previous
//
#include <hip/hip_runtime.h>

#define HW 128
#define HW2 16384
#define NEG 0.2f

typedef __attribute__((ext_vector_type(8))) short short8;
typedef __attribute__((ext_vector_type(4))) float f32x4;

__device__ __forceinline__ float lrelu(float v) { return v >= 0.f ? v : NEG * v; }
__device__ __forceinline__ unsigned short f2bf(float f) {
    unsigned int u = __float_as_uint(f);
    u = (u + 0x7fffu + ((u >> 16) & 1u)) >> 16;   // RNE
    return (unsigned short)u;
}
__device__ __forceinline__ float bf2f(unsigned short h) {
    return __uint_as_float(((unsigned int)h) << 16);
}

// ---------------------------------------------------------------------------
// Weight repack fp32 [M][Cin][3][3] -> bf16 padded [Mpad][Kpad],
// Kpad = (Cin/8)*96; layout: [g*96 + c_local*9 + tap], zeros in [72,96) pad
// and in rows co >= validM (offset conv padded 18->64).
// ---------------------------------------------------------------------------
struct WSeg { const float* s; unsigned short* d; int K9; int Kpad; int validM; int n; };
struct WArgs { WSeg seg[9]; };

__global__ void wrepack_kernel(WArgs a)
{
    const WSeg sg = a.seg[blockIdx.y];
    int i = blockIdx.x * 256 + threadIdx.x;
    if (i >= sg.n) return;
    int co = i / sg.Kpad, r = i - co * sg.Kpad;
    int g = r / 96, q = r - g * 96;
    unsigned short v = 0;
    if (co < sg.validM && q < 72) {
        int cl = q / 9, tap = q - 9 * cl;
        v = f2bf(sg.s[(size_t)co * sg.K9 + (g * 8 + cl) * 9 + tap]);
    }
    sg.d[i] = v;
}

// ---------------------------------------------------------------------------
// Fused producer+GEMM kernel.
// SRCF: 0 = im2col from fp32 planes, 1 = im2col from bf16 planes,
//       2 = deformable bilinear gather from bf16 planes (+fp32 offsets).
// Block: 256 threads, 64 px (2x32 tile), all Cout (MTW co-tiles/wave).
// Per 8-channel group: stage patch -> LDS, build col chunk Cs[64][96pad] in
// LDS, 3 MFMA K-steps (A = repacked weights direct from global/L2).
// mode 0: bf16 out + leaky; mode 1: fp32 out + leaky; mode 2: fp32 out,
// no leaky, co<18 only, stride 18 (offset conv).
// ---------------------------------------------------------------------------
template <int MTW, int SRCF>
__global__ __launch_bounds__(256, (MTW == 2 && SRCF == 2) ? 3 : 4)
void fused_kernel(
    const void* __restrict__ actv, const float* __restrict__ off,
    const unsigned short* __restrict__ wpad, const float* __restrict__ bias,
    unsigned short* __restrict__ outb, float* __restrict__ outf,
    int Cin, int Cout, int mode)
{
    constexpr int PSZ = (SRCF == 2) ? 3200 : 1088;   // floats: 8ch x (10x40 | 4x34)
    constexpr int CSTR = 104;                        // Cs row stride (shorts), 16B mult
    constexpr int SMB0 = PSZ * 4 + 64 * CSTR * 2;
    constexpr int SMB = SMB0 > 18432 ? SMB0 : 18432; // epilogue Es needs 128*72*2
    __shared__ char smem[SMB];
    float* patch = (float*)smem;
    unsigned short* Cs = (unsigned short*)(smem + PSZ * 4);
    unsigned short* Es = (unsigned short*)smem;

    const int t = threadIdx.x;
    const int tile = blockIdx.x, b = blockIdx.z;
    const int lane = t & 63, wv = t >> 6, quad = lane >> 4, l15 = lane & 15;
    const int y0 = (tile >> 2) * 2, x0 = (tile & 3) * 32;
    const int Kpad = (Cin >> 3) * 96;

    // zero Cs pad region [72,96) once (rows 64, 3 x uint4 each)
    if (t < 192) {
        int p = t / 3, j = t - 3 * p;
        uint4 z; z.x = z.y = z.z = z.w = 0;
        *(uint4*)&Cs[p * CSTR + 72 + j * 8] = z;
    }

    // ---- tap parameters (channel-invariant) ----
    int sp_[3], sk_[3], svalid[3], spi[3];
    float swt[3][4];
    int sidx[3][4];
    int fast = 1;

    if (SRCF == 2) {
        int allin = 1;
        const float* offb = off + (size_t)b * 18 * HW2;
#pragma unroll
        for (int s = 0; s < 3; ++s) {
            int task = t + s * 256;
            svalid[s] = task < 576;
            int task2 = svalid[s] ? task : 0;
            int p = task2 / 9, k = task2 - 9 * p;
            sp_[s] = p; sk_[s] = k;
            int ly = p >> 5, lx = p & 31;
            int yy = y0 + ly, xx = x0 + lx;
            float dy = offb[(2 * k) * HW2 + yy * HW + xx];
            float dx = offb[(2 * k + 1) * HW2 + yy * HW + xx];
            float py = (float)(yy + k / 3 - 1) + dy;
            float px = (float)(xx + k % 3 - 1) + dx;
            float fy = floorf(py), fx = floorf(px);
            float wy = py - fy, wx = px - fx;
            int iy = (int)fy, ix = (int)fx, iy1 = iy + 1, ix1 = ix + 1;
            float vy0 = (iy >= 0 && iy < HW) ? 1.f : 0.f;
            float vy1 = (iy1 >= 0 && iy1 < HW) ? 1.f : 0.f;
            float vx0 = (ix >= 0 && ix < HW) ? 1.f : 0.f;
            float vx1 = (ix1 >= 0 && ix1 < HW) ? 1.f : 0.f;
            int cy0 = min(max(iy, 0), HW - 1), cy1 = min(max(iy1, 0), HW - 1);
            int cx0 = min(max(ix, 0), HW - 1), cx1 = min(max(ix1, 0), HW - 1);
            swt[s][0] = (1.f - wy) * (1.f - wx) * vy0 * vx0;
            swt[s][1] = (1.f - wy) * wx * vy0 * vx1;
            swt[s][2] = wy * (1.f - wx) * vy1 * vx0;
            swt[s][3] = wy * wx * vy1 * vx1;
            sidx[s][0] = cy0 * HW + cx0;
            sidx[s][1] = cy0 * HW + cx1;
            sidx[s][2] = cy1 * HW + cx0;
            sidx[s][3] = cy1 * HW + cx1;
            bool ip = cy0 >= y0 - 4 && cy1 <= y0 + 5 &&
                      cx0 >= x0 - 4 && cx1 <= x0 + 35;
            if (!ip) allin = 0;
        }
        fast = __syncthreads_and(allin);
        if (fast) {
            const int pbase = (y0 - 4) * 40 + (x0 - 4);
#pragma unroll
            for (int s = 0; s < 3; ++s)
#pragma unroll
                for (int q = 0; q < 4; ++q) {
                    int gg = sidx[s][q];
                    sidx[s][q] = (gg >> 7) * 40 + (gg & 127) - pbase;
                }
        }
    } else {
#pragma unroll
        for (int s = 0; s < 3; ++s) {
            int task = t + s * 256;
            svalid[s] = task < 576;
            if (!svalid[s]) task = 0;
            int p = task / 9, k = task - 9 * p;
            sp_[s] = p; sk_[s] = k;
            int ly = p >> 5, lx = p & 31, ky = k / 3, kx = k - 3 * ky;
            spi[s] = (ly + ky) * 34 + lx + kx;
        }
    }

    f32x4 acc[MTW][4];
#pragma unroll
    for (int m = 0; m < MTW; ++m)
#pragma unroll
        for (int nt = 0; nt < 4; ++nt) acc[m][nt] = (f32x4)(0.f);

    const float* actf = (const float*)actv;
    const unsigned short* acth = (const unsigned short*)actv;
    const size_t bofs = (size_t)b * Cin * HW2;

    const int ngrp = Cin >> 3;
    for (int g = 0; g < ngrp; ++g) {
        const int c0 = g << 3;

        // ---- stage patch for 8 channels ----
        if (SRCF == 2) {
            if (fast) {
                for (int i = t; i < 3200; i += 256) {
                    int ch = i / 400, idx = i - ch * 400;
                    int r = idx / 40, cc = idx - r * 40;
                    int gy = y0 - 4 + r, gx = x0 - 4 + cc;
                    bool ok = gy >= 0 && gy < HW && gx >= 0 && gx < HW;
                    patch[i] = ok ? bf2f(acth[bofs + (size_t)(c0 + ch) * HW2 +
                                              gy * HW + gx]) : 0.f;
                }
            }
        } else {
            for (int i = t; i < 1088; i += 256) {
                int ch = i / 136, idx = i - ch * 136;
                int r = idx / 34, cc = idx - r * 34;
                int gy = y0 - 1 + r, gx = x0 - 1 + cc;
                bool ok = gy >= 0 && gy < HW && gx >= 0 && gx < HW;
                float v = 0.f;
                if (ok) {
                    size_t a = bofs + (size_t)(c0 + ch) * HW2 + gy * HW + gx;
                    v = (SRCF == 0) ? actf[a] : bf2f(acth[a]);
                }
                patch[i] = v;
            }
        }
        __syncthreads();

        // ---- build col chunk Cs[64][72 of 96] ----
        if (SRCF == 2) {
            if (fast) {
                for (int ch = 0; ch < 8; ++ch) {
                    const float* P = patch + ch * 400;
#pragma unroll
                    for (int s = 0; s < 3; ++s)
                        if (svalid[s]) {
                            float v = swt[s][0] * P[sidx[s][0]] +
                                      swt[s][1] * P[sidx[s][1]] +
                                      swt[s][2] * P[sidx[s][2]] +
                                      swt[s][3] * P[sidx[s][3]];
                            Cs[sp_[s] * CSTR + ch * 9 + sk_[s]] = f2bf(v);
                        }
                }
            } else {
                for (int ch = 0; ch < 8; ++ch) {
                    const unsigned short* pl = acth + bofs + (size_t)(c0 + ch) * HW2;
#pragma unroll
                    for (int s = 0; s < 3; ++s)
                        if (svalid[s]) {
                            float v = swt[s][0] * bf2f(pl[sidx[s][0]]) +
                                      swt[s][1] * bf2f(pl[sidx[s][1]]) +
                                      swt[s][2] * bf2f(pl[sidx[s][2]]) +
                                      swt[s][3] * bf2f(pl[sidx[s][3]]);
                            Cs[sp_[s] * CSTR + ch * 9 + sk_[s]] = f2bf(v);
                        }
                }
            }
        } else {
            for (int ch = 0; ch < 8; ++ch) {
                const float* P = patch + ch * 136;
#pragma unroll
                for (int s = 0; s < 3; ++s)
                    if (svalid[s])
                        Cs[sp_[s] * CSTR + ch * 9 + sk_[s]] = f2bf(P[spi[s]]);
            }
        }
        __syncthreads();

        // ---- 3 MFMA K-steps; A direct from global (L2-resident weights) ----
#pragma unroll
        for (int st = 0; st < 3; ++st) {
            const int kk0 = g * 96 + st * 32;
            short8 bfr[4];
#pragma unroll
            for (int nt = 0; nt < 4; ++nt)
                bfr[nt] = *(const short8*)&Cs[(nt * 16 + l15) * CSTR +
                                             st * 32 + quad * 8];
#pragma unroll
            for (int m = 0; m < MTW; ++m) {
                const int cb = (wv * MTW + m) * 16;
                short8 a = *(const short8*)(wpad + (size_t)(cb + l15) * Kpad +
                                            kk0 + quad * 8);
#pragma unroll
                for (int nt = 0; nt < 4; ++nt)
                    acc[m][nt] = __builtin_amdgcn_mfma_f32_16x16x32_bf16(
                        a, bfr[nt], acc[m][nt], 0, 0, 0);
            }
        }
        __syncthreads();
    }

    // ---- epilogue ----
    if (mode == 0) {
#pragma unroll
        for (int m = 0; m < MTW; ++m) {
            int cb = (wv * MTW + m) * 16;
#pragma unroll
            for (int nt = 0; nt < 4; ++nt)
#pragma unroll
                for (int r = 0; r < 4; ++r) {
                    int co = cb + quad * 4 + r;
                    int pxl = nt * 16 + l15;
                    float v = lrelu(acc[m][nt][r] + bias[co]);
                    Es[co * 72 + pxl] = f2bf(v);
                }
        }
        __syncthreads();
        unsigned short* ob = outb + (size_t)b * Cout * HW2;
        for (int tt = t; tt < Cout * 8; tt += 256) {
            int co = tt >> 3, seg = tt & 7;
            int ly = seg >> 2, lxb = (seg & 3) * 8;
            *(uint4*)(ob + (size_t)co * HW2 + (y0 + ly) * HW + x0 + lxb) =
                *(const uint4*)&Es[co * 72 + seg * 8];
        }
    } else {
        const int cstride = (mode == 2) ? 18 : Cout;
        float* of = outf + (size_t)b * cstride * HW2;
#pragma unroll
        for (int m = 0; m < MTW; ++m) {
            int cb = (wv * MTW + m) * 16;
#pragma unroll
            for (int nt = 0; nt < 4; ++nt)
#pragma unroll
                for (int r = 0; r < 4; ++r) {
                    int co = cb + quad * 4 + r;
                    if (mode == 2 && co >= 18) continue;
                    int pxl = nt * 16 + l15;
                    int yy = y0 + (pxl >> 5), xx = x0 + (pxl & 31);
                    float v = acc[m][nt][r] + bias[co];
                    if (mode == 1) v = lrelu(v);
                    of[(size_t)co * HW2 + yy * HW + xx] = v;
                }
        }
    }
}

// ---------------------------------------------------------------------------
extern "C" void kernel_launch(void* const* d_in, const int* in_sizes, int n_in,
                              void* d_out, int out_size, void* d_ws,
                              size_t ws_size, hipStream_t stream)
{
    const float* x = (const float*)d_in[0];
    const float* p[18];
    for (int i = 0; i < 18; ++i) p[i] = (const float*)d_in[1 + i];

    char* ws = (char*)d_ws;
    unsigned short* A1 = (unsigned short*)ws;              // 16.78 MB bf16 act
    unsigned short* A2 = (unsigned short*)(ws + 16777216); // 16.78 MB bf16 act
    float* OFF = (float*)(ws + 33554432);                  // 4.72 MB fp32 offsets
    unsigned short* WB = (unsigned short*)(ws + 38273024); // 2.16 MB weights

    unsigned short* Wc1 = WB;             // 128 x 768
    unsigned short* Wo1 = Wc1 + 98304;    // 64  x 1536 (18 valid)
    unsigned short* Wd1 = Wo1 + 98304;    // 128 x 1536
    unsigned short* Wc2 = Wd1 + 196608;   // 128 x 1536
    unsigned short* Wo2 = Wc2 + 196608;   // 64  x 1536 (18 valid)
    unsigned short* Wd2 = Wo2 + 98304;    // 128 x 1536
    unsigned short* Wc3 = Wd2 + 196608;   // 64  x 1536
    unsigned short* Wo3 = Wc3 + 98304;    // 64  x 768  (18 valid)
    unsigned short* Wd3 = Wo3 + 49152;    // 64  x 768

    WArgs wa;
    wa.seg[0] = {p[0],  Wc1,  576,  768, 128,  98304};
    wa.seg[1] = {p[2],  Wo1, 1152, 1536,  18,  98304};
    wa.seg[2] = {p[4],  Wd1, 1152, 1536, 128, 196608};
    wa.seg[3] = {p[6],  Wc2, 1152, 1536, 128, 196608};
    wa.seg[4] = {p[8],  Wo2, 1152, 1536,  18,  98304};
    wa.seg[5] = {p[10], Wd2, 1152, 1536, 128, 196608};
    wa.seg[6] = {p[12], Wc3, 1152, 1536,  64,  98304};
    wa.seg[7] = {p[14], Wo3,  576,  768,  18,  49152};
    wa.seg[8] = {p[16], Wd3,  576,  768,  64,  49152};
    wrepack_kernel<<<dim3(768, 9), 256, 0, stream>>>(wa);

    dim3 g(256, 1, 4);
    // stage 1: x(fp32,64) -> A1(128) ; A1 -> OFF ; A1+OFF -> A2(128)
    fused_kernel<2, 0><<<g, 256, 0, stream>>>(x, nullptr, Wc1, p[1], A1, nullptr, 64, 128, 0);
    fused_kernel<1, 1><<<g, 256, 0, stream>>>(A1, nullptr, Wo1, p[3], nullptr, OFF, 128, 64, 2);
    fused_kernel<2, 2><<<g, 256, 0, stream>>>(A1, OFF, Wd1, p[5], A2, nullptr, 128, 128, 0);
    // stage 2: A2 -> A1 ; A1 -> OFF ; A1+OFF -> A2
    fused_kernel<2, 1><<<g, 256, 0, stream>>>(A2, nullptr, Wc2, p[7], A1, nullptr, 128, 128, 0);
    fused_kernel<1, 1><<<g, 256, 0, stream>>>(A1, nullptr, Wo2, p[9], nullptr, OFF, 128, 64, 2);
    fused_kernel<2, 2><<<g, 256, 0, stream>>>(A1, OFF, Wd2, p[11], A2, nullptr, 128, 128, 0);
    // stage 3: A2 -> A1(64) ; A1 -> OFF ; A1+OFF -> d_out (fp32)
    fused_kernel<1, 1><<<g, 256, 0, stream>>>(A2, nullptr, Wc3, p[13], A1, nullptr, 128, 64, 0);
    fused_kernel<1, 1><<<g, 256, 0, stream>>>(A1, nullptr, Wo3, p[15], nullptr, OFF, 64, 64, 2);
    fused_kernel<1, 2><<<g, 256, 0, stream>>>(A1, OFF, Wd3, p[17], nullptr, (float*)d_out, 64, 64, 1);
}

// Round 6
// 467.218 us; speedup vs baseline: 12.4864x; 1.7398x over previous
//
#include <hip/hip_runtime.h>
#include <hip/hip_bf16.h>

#define HW 128
#define HW2 16384
#define NEG 0.2f

typedef __attribute__((ext_vector_type(8))) short short8;
typedef __attribute__((ext_vector_type(4))) float f32x4;

__device__ __forceinline__ float lrelu(float v) { return v >= 0.f ? v : NEG * v; }
__device__ __forceinline__ unsigned short f2bf(float f) {
    unsigned int u = __float_as_uint(f);
    u = (u + 0x7fffu + ((u >> 16) & 1u)) >> 16;
    return (unsigned short)u;
}
__device__ __forceinline__ unsigned int pk2(float a, float b) {
    __hip_bfloat162 h = __float22bfloat162_rn(float2{a, b});
    return *(unsigned int*)&h;
}
__device__ __forceinline__ float2 upk(unsigned int u) {
    return float2{__uint_as_float(u << 16), __uint_as_float(u & 0xffff0000u)};
}

// ---------------------------------------------------------------------------
// Weight repack fp32 [M][Cin][3][3] -> bf16 [Mpad][Kpad], Kpad=(Cin/8)*96,
// k-order TAP-MAJOR: k = g*96 + tap*8 + cl, taps 9..11 zero, rows>=validM zero.
// ---------------------------------------------------------------------------
struct WSeg { const float* s; unsigned short* d; int K9; int Kpad; int validM; int n; };
struct WArgs { WSeg seg[9]; };

__global__ void wrepack_kernel(WArgs a)
{
    const WSeg sg = a.seg[blockIdx.y];
    int i = blockIdx.x * 256 + threadIdx.x;
    if (i >= sg.n) return;
    int co = i / sg.Kpad, r = i - co * sg.Kpad;
    int g = r / 96, q = r - g * 96;
    int tap = q >> 3, cl = q & 7;
    unsigned short v = 0;
    if (co < sg.validM && tap < 9)
        v = f2bf(sg.s[(size_t)co * sg.K9 + (g * 8 + cl) * 9 + tap]);
    sg.d[i] = v;
}

// ---------------------------------------------------------------------------
// Fused plain conv. SRCF 0: fp32 planar input; 1: NHWC8 bf16 input.
// Patch [4 rows][34 px][8ch] bf16 in LDS; MFMA B-fragments read DIRECTLY from
// the patch (tap-shifted pixel = 8 contiguous bf16). No col build.
// mode 0: NHWC8 bf16 out + leaky; mode 2: planar fp32 out, co<18, no leaky.
// ---------------------------------------------------------------------------
template <int MTW, int SRCF>
__global__ __launch_bounds__(256, 4) void fused_conv(
    const void* __restrict__ actv, const unsigned short* __restrict__ wpad,
    const float* __restrict__ bias, unsigned short* __restrict__ outb,
    float* __restrict__ outf, int Cin, int Cout, int mode)
{
    constexpr int SMB = 64 * 136 * 2;          // Es; patch needs only 2176
    __shared__ char smem[SMB];
    unsigned short* patch = (unsigned short*)smem;   // [136 px][8ch]
    unsigned short* Es = (unsigned short*)smem;

    const int t = threadIdx.x;
    const int tile = blockIdx.x, b = blockIdx.z;
    const int lane = t & 63, wv = t >> 6, quad = lane >> 4, l15 = lane & 15;
    const int y0 = (tile >> 2) * 2, x0 = (tile & 3) * 32;
    const int Kpad = (Cin >> 3) * 96;
    const int ngrp = Cin >> 3;

    // staging task (t<136): one patch pixel
    const int pr = t / 34, pc = t - 34 * pr;
    const int gy = y0 - 1 + pr, gx = x0 - 1 + pc;
    const bool pok = (t < 136) && gy >= 0 && gy < HW && gx >= 0 && gx < HW;
    const int gp = pok ? gy * HW + gx : 0;

    const float* actf = (const float*)actv;
    const unsigned short* acth = (const unsigned short*)actv;
    const size_t bofs = (size_t)b * Cin * HW2;

    // B-fragment LDS byte addresses (channel-invariant)
    int baddr[3][4];
#pragma unroll
    for (int st = 0; st < 3; ++st) {
        int tap = st * 4 + quad; tap = tap > 8 ? 8 : tap;
        int ky = (tap * 11) >> 5, kx = tap - 3 * ky;
#pragma unroll
        for (int nt = 0; nt < 4; ++nt) {
            int p = nt * 16 + l15, ly = p >> 5, lx = p & 31;
            baddr[st][nt] = ((ly + ky) * 34 + lx + kx) * 16;
        }
    }
    size_t aoff[MTW];
#pragma unroll
    for (int m = 0; m < MTW; ++m)
        aoff[m] = (size_t)((wv * MTW + m) * 16 + l15) * Kpad + quad * 8;

    f32x4 acc[MTW][4];
#pragma unroll
    for (int m = 0; m < MTW; ++m)
#pragma unroll
        for (int nt = 0; nt < 4; ++nt) acc[m][nt] = (f32x4)(0.f);

    auto load_grp = [&](int g) -> uint4 {
        uint4 u; u.x = u.y = u.z = u.w = 0;
        if (!pok) return u;
        if (SRCF == 1) {
            u = *(const uint4*)(acth + bofs + ((size_t)g * HW2 + gp) * 8);
        } else {
            const float* pl = actf + bofs + (size_t)(g * 8) * HW2 + gp;
            float v0 = pl[0], v1 = pl[HW2], v2 = pl[2 * HW2], v3 = pl[3 * HW2];
            float v4 = pl[4 * HW2], v5 = pl[5 * HW2], v6 = pl[6 * HW2], v7 = pl[7 * HW2];
            u.x = pk2(v0, v1); u.y = pk2(v2, v3);
            u.z = pk2(v4, v5); u.w = pk2(v6, v7);
        }
        return u;
    };

    uint4 cur = load_grp(0);
    for (int g = 0; g < ngrp; ++g) {
        if (t < 136) *(uint4*)(patch + t * 8) = cur;
        __syncthreads();
        uint4 nxt = cur;
        if (g + 1 < ngrp) nxt = load_grp(g + 1);

        const unsigned short* wg = wpad + g * 96;
#pragma unroll
        for (int st = 0; st < 3; ++st) {
            short8 bfr[4];
#pragma unroll
            for (int nt = 0; nt < 4; ++nt)
                bfr[nt] = *(const short8*)((char*)patch + baddr[st][nt]);
#pragma unroll
            for (int m = 0; m < MTW; ++m) {
                short8 a = *(const short8*)(wg + aoff[m] + st * 32);
#pragma unroll
                for (int nt = 0; nt < 4; ++nt)
                    acc[m][nt] = __builtin_amdgcn_mfma_f32_16x16x32_bf16(
                        a, bfr[nt], acc[m][nt], 0, 0, 0);
            }
        }
        __syncthreads();
        cur = nxt;
    }

    if (mode == 0) {
        constexpr int ESTR = 136;
#pragma unroll
        for (int m = 0; m < MTW; ++m) {
            int cb = (wv * MTW + m) * 16;
#pragma unroll
            for (int nt = 0; nt < 4; ++nt) {
                int px = nt * 16 + l15;
                int co = cb + quad * 4;
                unsigned int u0 = pk2(lrelu(acc[m][nt][0] + bias[co]),
                                      lrelu(acc[m][nt][1] + bias[co + 1]));
                unsigned int u1 = pk2(lrelu(acc[m][nt][2] + bias[co + 2]),
                                      lrelu(acc[m][nt][3] + bias[co + 3]));
                uint2 u; u.x = u0; u.y = u1;
                *(uint2*)&Es[px * ESTR + co] = u;
            }
        }
        __syncthreads();
        const int ng8 = Cout >> 3;
        unsigned short* ob = outb + (size_t)b * Cout * HW2;
        for (int tt = t; tt < 64 * ng8; tt += 256) {
            int cg = tt >> 6, px = tt & 63;
            int gp2 = (y0 + (px >> 5)) * HW + x0 + (px & 31);
            *(uint4*)(ob + ((size_t)cg * HW2 + gp2) * 8) =
                *(const uint4*)&Es[px * ESTR + cg * 8];
        }
    } else {
        float* of = outf + (size_t)b * 18 * HW2;
#pragma unroll
        for (int m = 0; m < MTW; ++m) {
            int cb = (wv * MTW + m) * 16;
#pragma unroll
            for (int nt = 0; nt < 4; ++nt) {
                int px = nt * 16 + l15;
                int gp2 = (y0 + (px >> 5)) * HW + x0 + (px & 31);
#pragma unroll
                for (int r = 0; r < 4; ++r) {
                    int co = cb + quad * 4 + r;
                    if (co < 18)
                        of[(size_t)co * HW2 + gp2] = acc[m][nt][r] + bias[co];
                }
            }
        }
    }
}

// ---------------------------------------------------------------------------
// Fused deformable conv. NHWC8 bf16 input; bilinear col build channel-
// vectorized (one task = 8 channels: 4 corner b128 reads + 32 FMA + 1 b128
// write). Zero-filled patch + raw indices (no clamping) in fast path.
// mode 0: NHWC8 bf16 out + leaky; mode 1: planar fp32 out + leaky.
// ---------------------------------------------------------------------------
template <int MTW>
__global__ __launch_bounds__(256, 4) void fused_deform(
    const unsigned short* __restrict__ acth, const float* __restrict__ off,
    const unsigned short* __restrict__ wpad, const float* __restrict__ bias,
    unsigned short* __restrict__ outb, float* __restrict__ outf,
    int Cin, int Cout, int mode)
{
    constexpr int PATW = 41, PATP = 10 * PATW;           // 410 px
    constexpr int CSTR = 104;
    constexpr int SMB1 = PATP * 16 + 64 * CSTR * 2;      // 6560 + 13312
    constexpr int SMB = SMB1 > 17408 ? SMB1 : 17408;
    __shared__ char smem[SMB];
    unsigned short* patch = (unsigned short*)smem;       // [410 px][8ch] bf16
    unsigned short* Cs = (unsigned short*)(smem + PATP * 16);
    unsigned short* Es = (unsigned short*)smem;

    const int t = threadIdx.x;
    const int tile = blockIdx.x, b = blockIdx.z;
    const int lane = t & 63, wv = t >> 6, quad = lane >> 4, l15 = lane & 15;
    const int y0 = (tile >> 2) * 2, x0 = (tile & 3) * 32;
    const int Kpad = (Cin >> 3) * 96;
    const int ngrp = Cin >> 3;
    const int py0 = y0 - 4, px0 = x0 - 4;

    // zero Cs k-pad [72,96)
    if (t < 192) {
        int p = t / 3, j = t - 3 * p;
        uint4 z; z.x = z.y = z.z = z.w = 0;
        *(uint4*)&Cs[p * CSTR + 72 + j * 8] = z;
    }

    // ---- phase 0: tap params (slots t, t+256, t+512) ----
    int sp_[3], sk_[3], svalid[3];
    float swy[3], swx[3];
    int siy[3], six[3];
    int allin = 1;
    const float* offb = off + (size_t)b * 18 * HW2;
#pragma unroll
    for (int s = 0; s < 3; ++s) {
        int task = t + s * 256;
        svalid[s] = task < 576;
        int task2 = svalid[s] ? task : 0;
        int p = task2 / 9, k = task2 - 9 * p;
        sp_[s] = p; sk_[s] = k;
        int ly = p >> 5, lx = p & 31;
        int yy = y0 + ly, xx = x0 + lx;
        float dy = offb[(2 * k) * HW2 + yy * HW + xx];
        float dx = offb[(2 * k + 1) * HW2 + yy * HW + xx];
        float py = (float)(yy + k / 3 - 1) + dy;
        float px = (float)(xx + k % 3 - 1) + dx;
        float fy = floorf(py), fx = floorf(px);
        swy[s] = py - fy; swx[s] = px - fx;
        int iy = (int)fy, ix = (int)fx;
        siy[s] = iy; six[s] = ix;
        bool ip = iy >= py0 && iy + 1 <= y0 + 5 && ix >= px0 && ix + 1 <= x0 + 36;
        if (!ip) allin = 0;
    }
    const int fast = __syncthreads_and(allin);

    // staging slots: i0 = t (always <410), i1 = t+256 (if <410)
    const int r0 = t / PATW, c0_ = t - PATW * r0;
    const int gy0_ = py0 + r0, gx0_ = px0 + c0_;
    const bool ok0 = gy0_ >= 0 && gy0_ < HW && gx0_ >= 0 && gx0_ < HW;
    const int go0 = ok0 ? gy0_ * HW + gx0_ : 0;
    const int i1 = t + 256;
    const bool has1 = i1 < PATP;
    const int r1 = i1 / PATW, c1_ = i1 - PATW * r1;
    const int gy1_ = py0 + r1, gx1_ = px0 + c1_;
    const bool ok1 = has1 && gy1_ >= 0 && gy1_ < HW && gx1_ >= 0 && gx1_ < HW;
    const int go1 = ok1 ? gy1_ * HW + gx1_ : 0;

    const size_t bofs = (size_t)b * Cin * HW2;

    int baddr[3][4];
#pragma unroll
    for (int st = 0; st < 3; ++st)
#pragma unroll
        for (int nt = 0; nt < 4; ++nt)
            baddr[st][nt] = (nt * 16 + l15) * (CSTR * 2) + st * 64 + quad * 16;
    size_t aoff[MTW];
#pragma unroll
    for (int m = 0; m < MTW; ++m)
        aoff[m] = (size_t)((wv * MTW + m) * 16 + l15) * Kpad + quad * 8;

    f32x4 acc[MTW][4];
#pragma unroll
    for (int m = 0; m < MTW; ++m)
#pragma unroll
        for (int nt = 0; nt < 4; ++nt) acc[m][nt] = (f32x4)(0.f);

    // fast-path precomputes
    float w00[3], w01[3], w10[3], w11[3];
    int pbase[3];
#pragma unroll
    for (int s = 0; s < 3; ++s) {
        float wy = swy[s], wx = swx[s];
        w00[s] = (1.f - wy) * (1.f - wx);
        w01[s] = (1.f - wy) * wx;
        w10[s] = wy * (1.f - wx);
        w11[s] = wy * wx;
        pbase[s] = ((siy[s] - py0) * PATW + (six[s] - px0)) * 16;  // bytes
    }

    auto load0 = [&](int g) -> uint4 {
        uint4 u; u.x = u.y = u.z = u.w = 0;
        if (ok0) u = *(const uint4*)(acth + bofs + ((size_t)g * HW2 + go0) * 8);
        return u;
    };
    auto load1 = [&](int g) -> uint4 {
        uint4 u; u.x = u.y = u.z = u.w = 0;
        if (ok1) u = *(const uint4*)(acth + bofs + ((size_t)g * HW2 + go1) * 8);
        return u;
    };

    uint4 cur0 = load0(0), cur1 = load1(0);
    for (int g = 0; g < ngrp; ++g) {
        *(uint4*)(patch + t * 8) = cur0;
        if (has1) *(uint4*)(patch + i1 * 8) = cur1;
        __syncthreads();
        uint4 nxt0 = cur0, nxt1 = cur1;
        if (g + 1 < ngrp) { nxt0 = load0(g + 1); nxt1 = load1(g + 1); }

        // ---- col build: 8 channels per task ----
        if (fast) {
#pragma unroll
            for (int s = 0; s < 3; ++s) {
                if (!svalid[s]) continue;
                const char* base = (const char*)patch + pbase[s];
                uint4 ca = *(const uint4*)base;
                uint4 cb_ = *(const uint4*)(base + 16);
                uint4 cc = *(const uint4*)(base + PATW * 16);
                uint4 cd = *(const uint4*)(base + PATW * 16 + 16);
                uint4 ou;
                {
                    float2 a = upk(ca.x), b2 = upk(cb_.x), c2 = upk(cc.x), d2 = upk(cd.x);
                    ou.x = pk2(w00[s] * a.x + w01[s] * b2.x + w10[s] * c2.x + w11[s] * d2.x,
                               w00[s] * a.y + w01[s] * b2.y + w10[s] * c2.y + w11[s] * d2.y);
                }
                {
                    float2 a = upk(ca.y), b2 = upk(cb_.y), c2 = upk(cc.y), d2 = upk(cd.y);
                    ou.y = pk2(w00[s] * a.x + w01[s] * b2.x + w10[s] * c2.x + w11[s] * d2.x,
                               w00[s] * a.y + w01[s] * b2.y + w10[s] * c2.y + w11[s] * d2.y);
                }
                {
                    float2 a = upk(ca.z), b2 = upk(cb_.z), c2 = upk(cc.z), d2 = upk(cd.z);
                    ou.z = pk2(w00[s] * a.x + w01[s] * b2.x + w10[s] * c2.x + w11[s] * d2.x,
                               w00[s] * a.y + w01[s] * b2.y + w10[s] * c2.y + w11[s] * d2.y);
                }
                {
                    float2 a = upk(ca.w), b2 = upk(cb_.w), c2 = upk(cc.w), d2 = upk(cd.w);
                    ou.w = pk2(w00[s] * a.x + w01[s] * b2.x + w10[s] * c2.x + w11[s] * d2.x,
                               w00[s] * a.y + w01[s] * b2.y + w10[s] * c2.y + w11[s] * d2.y);
                }
                *(uint4*)&Cs[sp_[s] * CSTR + sk_[s] * 8] = ou;
            }
        } else {
#pragma unroll
            for (int s = 0; s < 3; ++s) {
                if (!svalid[s]) continue;
                int iy = siy[s], ix = six[s], iy1 = iy + 1, ix1 = ix + 1;
                float vy0 = (iy >= 0 && iy < HW) ? 1.f : 0.f;
                float vy1 = (iy1 >= 0 && iy1 < HW) ? 1.f : 0.f;
                float vx0 = (ix >= 0 && ix < HW) ? 1.f : 0.f;
                float vx1 = (ix1 >= 0 && ix1 < HW) ? 1.f : 0.f;
                int cy0 = min(max(iy, 0), HW - 1), cy1 = min(max(iy1, 0), HW - 1);
                int cx0 = min(max(ix, 0), HW - 1), cx1 = min(max(ix1, 0), HW - 1);
                float m00 = w00[s] * vy0 * vx0, m01 = w01[s] * vy0 * vx1;
                float m10 = w10[s] * vy1 * vx0, m11 = w11[s] * vy1 * vx1;
                const unsigned short* gb = acth + bofs + (size_t)g * HW2 * 8;
                uint4 ca = *(const uint4*)(gb + (size_t)(cy0 * HW + cx0) * 8);
                uint4 cb_ = *(const uint4*)(gb + (size_t)(cy0 * HW + cx1) * 8);
                uint4 cc = *(const uint4*)(gb + (size_t)(cy1 * HW + cx0) * 8);
                uint4 cd = *(const uint4*)(gb + (size_t)(cy1 * HW + cx1) * 8);
                uint4 ou;
                {
                    float2 a = upk(ca.x), b2 = upk(cb_.x), c2 = upk(cc.x), d2 = upk(cd.x);
                    ou.x = pk2(m00 * a.x + m01 * b2.x + m10 * c2.x + m11 * d2.x,
                               m00 * a.y + m01 * b2.y + m10 * c2.y + m11 * d2.y);
                }
                {
                    float2 a = upk(ca.y), b2 = upk(cb_.y), c2 = upk(cc.y), d2 = upk(cd.y);
                    ou.y = pk2(m00 * a.x + m01 * b2.x + m10 * c2.x + m11 * d2.x,
                               m00 * a.y + m01 * b2.y + m10 * c2.y + m11 * d2.y);
                }
                {
                    float2 a = upk(ca.z), b2 = upk(cb_.z), c2 = upk(cc.z), d2 = upk(cd.z);
                    ou.z = pk2(m00 * a.x + m01 * b2.x + m10 * c2.x + m11 * d2.x,
                               m00 * a.y + m01 * b2.y + m10 * c2.y + m11 * d2.y);
                }
                {
                    float2 a = upk(ca.w), b2 = upk(cb_.w), c2 = upk(cc.w), d2 = upk(cd.w);
                    ou.w = pk2(m00 * a.x + m01 * b2.x + m10 * c2.x + m11 * d2.x,
                               m00 * a.y + m01 * b2.y + m10 * c2.y + m11 * d2.y);
                }
                *(uint4*)&Cs[sp_[s] * CSTR + sk_[s] * 8] = ou;
            }
        }
        __syncthreads();

        const unsigned short* wg = wpad + g * 96;
#pragma unroll
        for (int st = 0; st < 3; ++st) {
            short8 bfr[4];
#pragma unroll
            for (int nt = 0; nt < 4; ++nt)
                bfr[nt] = *(const short8*)((char*)Cs + baddr[st][nt]);
#pragma unroll
            for (int m = 0; m < MTW; ++m) {
                short8 a = *(const short8*)(wg + aoff[m] + st * 32);
#pragma unroll
                for (int nt = 0; nt < 4; ++nt)
                    acc[m][nt] = __builtin_amdgcn_mfma_f32_16x16x32_bf16(
                        a, bfr[nt], acc[m][nt], 0, 0, 0);
            }
        }
        __syncthreads();
        cur0 = nxt0; cur1 = nxt1;
    }

    if (mode == 0) {
        constexpr int ESTR = 136;
#pragma unroll
        for (int m = 0; m < MTW; ++m) {
            int cb = (wv * MTW + m) * 16;
#pragma unroll
            for (int nt = 0; nt < 4; ++nt) {
                int px = nt * 16 + l15;
                int co = cb + quad * 4;
                unsigned int u0 = pk2(lrelu(acc[m][nt][0] + bias[co]),
                                      lrelu(acc[m][nt][1] + bias[co + 1]));
                unsigned int u1 = pk2(lrelu(acc[m][nt][2] + bias[co + 2]),
                                      lrelu(acc[m][nt][3] + bias[co + 3]));
                uint2 u; u.x = u0; u.y = u1;
                *(uint2*)&Es[px * ESTR + co] = u;
            }
        }
        __syncthreads();
        const int ng8 = Cout >> 3;
        unsigned short* ob = outb + (size_t)b * Cout * HW2;
        for (int tt = t; tt < 64 * ng8; tt += 256) {
            int cg = tt >> 6, px = tt & 63;
            int gp2 = (y0 + (px >> 5)) * HW + x0 + (px & 31);
            *(uint4*)(ob + ((size_t)cg * HW2 + gp2) * 8) =
                *(const uint4*)&Es[px * ESTR + cg * 8];
        }
    } else {
        float* of = outf + (size_t)b * Cout * HW2;
#pragma unroll
        for (int m = 0; m < MTW; ++m) {
            int cb = (wv * MTW + m) * 16;
#pragma unroll
            for (int nt = 0; nt < 4; ++nt) {
                int px = nt * 16 + l15;
                int gp2 = (y0 + (px >> 5)) * HW + x0 + (px & 31);
#pragma unroll
                for (int r = 0; r < 4; ++r) {
                    int co = cb + quad * 4 + r;
                    of[(size_t)co * HW2 + gp2] = lrelu(acc[m][nt][r] + bias[co]);
                }
            }
        }
    }
}

// ---------------------------------------------------------------------------
extern "C" void kernel_launch(void* const* d_in, const int* in_sizes, int n_in,
                              void* d_out, int out_size, void* d_ws,
                              size_t ws_size, hipStream_t stream)
{
    const float* x = (const float*)d_in[0];
    const float* p[18];
    for (int i = 0; i < 18; ++i) p[i] = (const float*)d_in[1 + i];

    char* ws = (char*)d_ws;
    unsigned short* A1 = (unsigned short*)ws;              // NHWC8 bf16
    unsigned short* A2 = (unsigned short*)(ws + 16777216);
    float* OFF = (float*)(ws + 33554432);                  // fp32 planar 18ch
    unsigned short* WB = (unsigned short*)(ws + 38273024);

    unsigned short* Wc1 = WB;             // 128 x 768
    unsigned short* Wo1 = Wc1 + 98304;    // 64  x 1536 (18 valid)
    unsigned short* Wd1 = Wo1 + 98304;    // 128 x 1536
    unsigned short* Wc2 = Wd1 + 196608;   // 128 x 1536
    unsigned short* Wo2 = Wc2 + 196608;   // 64  x 1536 (18 valid)
    unsigned short* Wd2 = Wo2 + 98304;    // 128 x 1536
    unsigned short* Wc3 = Wd2 + 196608;   // 64  x 1536
    unsigned short* Wo3 = Wc3 + 98304;    // 64  x 768  (18 valid)
    unsigned short* Wd3 = Wo3 + 49152;    // 64  x 768

    WArgs wa;
    wa.seg[0] = {p[0],  Wc1,  576,  768, 128,  98304};
    wa.seg[1] = {p[2],  Wo1, 1152, 1536,  18,  98304};
    wa.seg[2] = {p[4],  Wd1, 1152, 1536, 128, 196608};
    wa.seg[3] = {p[6],  Wc2, 1152, 1536, 128, 196608};
    wa.seg[4] = {p[8],  Wo2, 1152, 1536,  18,  98304};
    wa.seg[5] = {p[10], Wd2, 1152, 1536, 128, 196608};
    wa.seg[6] = {p[12], Wc3, 1152, 1536,  64,  98304};
    wa.seg[7] = {p[14], Wo3,  576,  768,  18,  49152};
    wa.seg[8] = {p[16], Wd3,  576,  768,  64,  49152};
    wrepack_kernel<<<dim3(768, 9), 256, 0, stream>>>(wa);

    dim3 g(256, 1, 4);
    // stage 1
    fused_conv<2, 0><<<g, 256, 0, stream>>>(x, Wc1, p[1], A1, nullptr, 64, 128, 0);
    fused_conv<1, 1><<<g, 256, 0, stream>>>(A1, Wo1, p[3], nullptr, OFF, 128, 64, 2);
    fused_deform<2><<<g, 256, 0, stream>>>(A1, OFF, Wd1, p[5], A2, nullptr, 128, 128, 0);
    // stage 2
    fused_conv<2, 1><<<g, 256, 0, stream>>>(A2, Wc2, p[7], A1, nullptr, 128, 128, 0);
    fused_conv<1, 1><<<g, 256, 0, stream>>>(A1, Wo2, p[9], nullptr, OFF, 128, 64, 2);
    fused_deform<2><<<g, 256, 0, stream>>>(A1, OFF, Wd2, p[11], A2, nullptr, 128, 128, 0);
    // stage 3
    fused_conv<1, 1><<<g, 256, 0, stream>>>(A2, Wc3, p[13], A1, nullptr, 128, 64, 0);
    fused_conv<1, 1><<<g, 256, 0, stream>>>(A1, Wo3, p[15], nullptr, OFF, 64, 64, 2);
    fused_deform<1><<<g, 256, 0, stream>>>(A1, OFF, Wd3, p[17], nullptr, (float*)d_out, 64, 64, 1);
}